// Round 4
// baseline (1368.583 us; speedup 1.0000x reference)
//
#include <hip/hip_runtime.h>
#include <hip/hip_bf16.h>

typedef unsigned short u16;
typedef unsigned int   u32;
typedef __attribute__((ext_vector_type(8))) short short8;   // 8 bf16 (4 VGPRs)
typedef __attribute__((ext_vector_type(4))) float f32x4;

#define BBt 128
#define SS 128
#define RR 32
#define NEx 3
#define MB (1024 * 1024)

static __device__ __forceinline__ float bs2f(u16 u){ return __uint_as_float(((u32)u) << 16); }
static __device__ __forceinline__ u16 f2bs(float x){
    u32 u = __float_as_uint(x);
    u += 0x7fff + ((u >> 16) & 1);          // RNE
    return (u16)(u >> 16);
}
static __device__ __forceinline__ u32 pkbf(float a, float b){   // pack 2 fp32 -> 2 bf16 (RNE)
    u32 r; asm("v_cvt_pk_bf16_f32 %0, %1, %2" : "=v"(r) : "v"(a), "v"(b)); return r;
}
static __device__ __forceinline__ float ldany(const float* p){ return *p; }
static __device__ __forceinline__ float ldany(const u16* p){ return bs2f(*p); }

// ===========================================================================
// MFMA GEMM v2: C[M,N] = A[M,K] @ W[K,N] (+bias) (+Res), dual-output split.
// BM=128, BN=128, BK=32, 256 threads (4 waves 2x2).
// A: fp32 or bf16, LDS double-buffered (one barrier/K-step).
// W: fp32 row-major, B-frags loaded DIRECTLY from global (L2-resident; no
//    LDS transpose). Optional W2/bias2/C2 split columns at Nsplit (fused
//    K+V projections).
// Frag conventions (validated): A lane(l15,quad)=A[l15][quad*8+i];
// B lane(l15,quad)=W[quad*8+i][l15]; C/D col=l15, row=quad*4+reg.
// M % 128 == 0, K % 32 == 0. Batched via z (A,W,W2,C,C2 strided).
// ===========================================================================
template<typename TA, typename TRes, typename TC>
__global__ __launch_bounds__(256) void gemm_bb(
    const TA* __restrict__ A, int lda, long long sA,
    const float* __restrict__ W, const float* __restrict__ W2, int ldw, long long sW,
    const float* __restrict__ bias, const float* __restrict__ bias2,
    const TRes* __restrict__ Res, int ldr,
    TC* __restrict__ C, TC* __restrict__ C2, int ldc, long long sC,
    int K, int Ncols, int Nsplit)
{
    int bz = blockIdx.z;
    A += (long long)bz * sA;
    W += (long long)bz * sW;
    if (W2) W2 += (long long)bz * sW;
    C += (long long)bz * sC;
    if (C2) C2 += (long long)bz * sC;

    __shared__ __align__(16) u16 As[2][128][40];   // double-buffered A tile

    int tid = threadIdx.x;
    long long row0 = (long long)blockIdx.y * 128;
    int col0 = blockIdx.x * 128;

    int wid = tid >> 6, lane = tid & 63;
    int wm = (wid >> 1) * 64, wn = (wid & 1) * 64;
    int l15 = lane & 15, quad = lane >> 4;

    f32x4 acc[4][4];
    #pragma unroll
    for (int i = 0; i < 4; ++i)
        #pragma unroll
        for (int j = 0; j < 4; ++j)
            acc[i][j] = (f32x4){0.f, 0.f, 0.f, 0.f};

    int ar = tid >> 1, ak = (tid & 1) * 16;

    {   // ---- prologue: stage K-step 0 into buffer 0 ----
        const TA* src = A + (row0 + ar) * lda + ak;
        if constexpr (sizeof(TA) == 4) {
            float4 f0 = *(const float4*)(src);
            float4 f1 = *(const float4*)(src + 4);
            float4 f2 = *(const float4*)(src + 8);
            float4 f3 = *(const float4*)(src + 12);
            u32 t0[4] = {pkbf(f0.x,f0.y), pkbf(f0.z,f0.w), pkbf(f1.x,f1.y), pkbf(f1.z,f1.w)};
            u32 t1[4] = {pkbf(f2.x,f2.y), pkbf(f2.z,f2.w), pkbf(f3.x,f3.y), pkbf(f3.z,f3.w)};
            *(uint4*)&As[0][ar][ak]     = *(uint4*)t0;
            *(uint4*)&As[0][ar][ak + 8] = *(uint4*)t1;
        } else {
            *(uint4*)&As[0][ar][ak]     = *(const uint4*)(src);
            *(uint4*)&As[0][ar][ak + 8] = *(const uint4*)(src + 8);
        }
    }
    __syncthreads();

    int nsteps = K >> 5;
    for (int s = 0; s < nsteps; ++s) {
        int p = s & 1;
        // ---- prefetch next A tile into regs (issue early) ----
        uint4 st0, st1;
        bool have = (s + 1 < nsteps);
        if (have) {
            const TA* src = A + (row0 + ar) * lda + ((s + 1) << 5) + ak;
            if constexpr (sizeof(TA) == 4) {
                float4 f0 = *(const float4*)(src);
                float4 f1 = *(const float4*)(src + 4);
                float4 f2 = *(const float4*)(src + 8);
                float4 f3 = *(const float4*)(src + 12);
                u32 t0[4] = {pkbf(f0.x,f0.y), pkbf(f0.z,f0.w), pkbf(f1.x,f1.y), pkbf(f1.z,f1.w)};
                u32 t1[4] = {pkbf(f2.x,f2.y), pkbf(f2.z,f2.w), pkbf(f3.x,f3.y), pkbf(f3.z,f3.w)};
                st0 = *(uint4*)t0; st1 = *(uint4*)t1;
            } else {
                st0 = *(const uint4*)(src);
                st1 = *(const uint4*)(src + 8);
            }
        }
        // ---- A frags from LDS ----
        short8 af[4];
        #pragma unroll
        for (int mt = 0; mt < 4; ++mt)
            af[mt] = *(const short8*)&As[p][wm + mt * 16 + l15][quad * 8];
        // ---- B frags direct from global (L2) + MFMA ----
        int kb = (s << 5) + quad * 8;
        #pragma unroll
        for (int nt = 0; nt < 4; ++nt) {
            int col = col0 + wn + nt * 16 + l15;
            const float* wp = W; int wc = col;
            if (W2 && col >= Nsplit) { wp = W2; wc = col - Nsplit; }
            bool ok = (col < Ncols);
            const float* pw = wp + (long long)kb * ldw + wc;
            union { u32 u[4]; short8 s8; } bb;
            #pragma unroll
            for (int i = 0; i < 4; ++i) {
                float w0 = 0.f, w1 = 0.f;
                if (ok) {
                    w0 = pw[(2 * i) * ldw];
                    w1 = pw[(2 * i + 1) * ldw];
                }
                bb.u[i] = pkbf(w0, w1);
            }
            #pragma unroll
            for (int mt = 0; mt < 4; ++mt)
                acc[mt][nt] = __builtin_amdgcn_mfma_f32_16x16x32_bf16(
                    af[mt], bb.s8, acc[mt][nt], 0, 0, 0);
        }
        // ---- commit next tile, one barrier per step ----
        if (have) {
            *(uint4*)&As[p ^ 1][ar][ak]     = st0;
            *(uint4*)&As[p ^ 1][ar][ak + 8] = st1;
        }
        __syncthreads();
    }

    // ---- epilogue: C/D layout col=lane&15, row=quad*4+reg ----
    #pragma unroll
    for (int mt = 0; mt < 4; ++mt) {
        #pragma unroll
        for (int r = 0; r < 4; ++r) {
            long long row = row0 + wm + mt * 16 + quad * 4 + r;
            #pragma unroll
            for (int nt = 0; nt < 4; ++nt) {
                int col = col0 + wn + nt * 16 + l15;
                if (col >= Ncols) continue;
                float v = acc[mt][nt][r];
                if (bias2 && col >= Nsplit) v += bias2[col - Nsplit];
                else if (bias)              v += bias[col];
                if (Res) v += ldany(&Res[row * ldr + col]);
                TC* dst = (C2 && col >= Nsplit) ? (C2 + row * ldc + (col - Nsplit))
                                                : (C  + row * ldc + col);
                if constexpr (sizeof(TC) == 4) *dst = v;
                else                           *dst = f2bs(v);
            }
        }
    }
}

// ===========================================================================
// MFMA flash-less attention, bf16 in/out. Block per (head h, batch b).
// 4 waves x 32 query rows. Q[128,64], K[L,64], V[L,64] per (b,h), L <= 128.
// S = Q @ K^T : kS natural [kv][d]; O = P @ V : vT transposed [d][kv].
// P round-trips through per-wave LDS (aliased over dead kS; one barrier).
// Causal waves skip tiles: nt <= 2w+1, ks <= w.
// out may alias Q (Q fully register-resident before any store).
// ===========================================================================
__global__ __launch_bounds__(256) void attn_mfma_k(
    const u16* __restrict__ Q, const u16* __restrict__ K,
    const u16* __restrict__ V, u16* __restrict__ out,
    int L, int causal)
{
    int h = blockIdx.x, b = blockIdx.y;
    int tid = threadIdx.x;
    int w = tid >> 6, lane = tid & 63;
    int l15 = lane & 15, quad = lane >> 4;

    int NTP = (L + 15) >> 4;          // padded kv tiles (6 or 8)
    int Lp  = NTP * 16;               // 96 or 128
    int ntmax = causal ? (2 * w + 1) : (NTP - 1);        // wave-uniform
    int ksmax = causal ? w : (((L + 31) >> 5) - 1);      // wave-uniform

    __shared__ __align__(16) u16 vT[64][136];            // V^T [d][kv], 17408 B
    __shared__ __align__(16) u16 pool[4][32][136];       // pS (aliases kS), 34816 B
    u16 (*kS)[72] = (u16(*)[72])&pool[0][0][0];          // [128][72] = 18432 B

    // ---- stage K natural [kv][d] (zero-pad rows >= L) ----
    for (int i = tid; i < Lp * 8; i += 256) {
        int r = i >> 3, c8 = i & 7;
        uint4 val = {0u, 0u, 0u, 0u};
        if (r < L) val = *(const uint4*)&K[((long long)b * L + r) * 512 + h * 64 + c8 * 8];
        *(uint4*)&kS[r][c8 * 8] = val;
    }
    // ---- stage V transposed [d][kv] (zero-pad kv >= L) ----
    for (int i = tid; i < 512; i += 256) {       // dg = i>>6 in 0..7, kp = i&63
        int kp = i & 63, dg = i >> 6;
        int kv0 = kp * 2;
        if (kv0 < Lp) {
            uint4 r0 = {0u,0u,0u,0u}, r1 = {0u,0u,0u,0u};
            if (kv0 < L)     r0 = *(const uint4*)&V[((long long)b * L + kv0    ) * 512 + h * 64 + dg * 8];
            if (kv0 + 1 < L) r1 = *(const uint4*)&V[((long long)b * L + kv0 + 1) * 512 + h * 64 + dg * 8];
            u32 w0[4] = {r0.x, r0.y, r0.z, r0.w};
            u32 w1[4] = {r1.x, r1.y, r1.z, r1.w};
            #pragma unroll
            for (int j = 0; j < 4; ++j) {
                *(u32*)&vT[dg * 8 + 2 * j    ][kv0] = (w0[j] & 0xffffu) | (w1[j] << 16);
                *(u32*)&vT[dg * 8 + 2 * j + 1][kv0] = (w0[j] >> 16) | (w1[j] & 0xffff0000u);
            }
        }
    }

    // ---- Q fragments direct from global (A-frag layout) ----
    short8 qf[2][2];
    #pragma unroll
    for (int mt = 0; mt < 2; ++mt)
        #pragma unroll
        for (int ks = 0; ks < 2; ++ks)
            qf[mt][ks] = *(const short8*)&Q[((long long)b * 128 + w * 32 + mt * 16 + l15) * 512
                                            + h * 64 + ks * 32 + quad * 8];
    __syncthreads();

    // ---- S = Q @ K^T (tiles guarded by wave-uniform ntmax) ----
    f32x4 sacc[2][8];
    #pragma unroll
    for (int mt = 0; mt < 2; ++mt)
        #pragma unroll
        for (int nt = 0; nt < 8; ++nt)
            sacc[mt][nt] = (f32x4){0.f, 0.f, 0.f, 0.f};
    #pragma unroll
    for (int nt = 0; nt < 8; ++nt) {
        if (nt <= ntmax) {
            short8 kf0 = *(const short8*)&kS[nt * 16 + l15][quad * 8];
            short8 kf1 = *(const short8*)&kS[nt * 16 + l15][32 + quad * 8];
            #pragma unroll
            for (int mt = 0; mt < 2; ++mt) {
                sacc[mt][nt] = __builtin_amdgcn_mfma_f32_16x16x32_bf16(qf[mt][0], kf0, sacc[mt][nt], 0, 0, 0);
                sacc[mt][nt] = __builtin_amdgcn_mfma_f32_16x16x32_bf16(qf[mt][1], kf1, sacc[mt][nt], 0, 0, 0);
            }
        }
    }

    // ---- softmax over rows (cols = l15 lanes x nt tiles); scale 1/8 folded ----
    float pm[2][4], ls[2][4];
    #pragma unroll
    for (int mt = 0; mt < 2; ++mt) {
        #pragma unroll
        for (int r = 0; r < 4; ++r) pm[mt][r] = -1e30f;
        #pragma unroll
        for (int nt = 0; nt < 8; ++nt) {
            if (nt <= ntmax) {
                int col = nt * 16 + l15;
                #pragma unroll
                for (int r = 0; r < 4; ++r) {
                    int rowq = w * 32 + mt * 16 + quad * 4 + r;
                    bool bad = (col >= L) || (causal && col > rowq);
                    float sv = bad ? -1e30f : sacc[mt][nt][r];
                    sacc[mt][nt][r] = sv;
                    pm[mt][r] = fmaxf(pm[mt][r], sv);
                }
            }
        }
        #pragma unroll
        for (int r = 0; r < 4; ++r) {
            float mx = pm[mt][r];
            #pragma unroll
            for (int o = 1; o <= 8; o <<= 1) mx = fmaxf(mx, __shfl_xor(mx, o));
            pm[mt][r] = mx * 0.125f;           // scaled max
            ls[mt][r] = 0.f;
        }
        #pragma unroll
        for (int nt = 0; nt < 8; ++nt) {
            if (nt <= ntmax) {
                #pragma unroll
                for (int r = 0; r < 4; ++r) {
                    float p = __expf(fmaf(sacc[mt][nt][r], 0.125f, -pm[mt][r]));
                    sacc[mt][nt][r] = p;
                    ls[mt][r] += p;
                }
            }
        }
        #pragma unroll
        for (int r = 0; r < 4; ++r) {
            float sm = ls[mt][r];
            #pragma unroll
            for (int o = 1; o <= 8; o <<= 1) sm += __shfl_xor(sm, o);
            ls[mt][r] = 1.f / sm;
        }
    }

    __syncthreads();   // kS dead -> reuse as per-wave P tiles

    // ---- P -> bf16 -> per-wave LDS (pack col pairs via shfl, even l15 writes) ----
    u16 (*pW)[136] = (u16(*)[136])&pool[w][0][0];
    bool wl = (l15 & 1) == 0;
    #pragma unroll
    for (int mt = 0; mt < 2; ++mt)
        #pragma unroll
        for (int nt = 0; nt < 8; ++nt) {
            if (nt <= ntmax) {
                #pragma unroll
                for (int r = 0; r < 4; ++r) {
                    float pv = sacc[mt][nt][r];
                    float po = __shfl_xor(pv, 1);
                    if (wl) {
                        u32 packed = (u32)f2bs(pv) | ((u32)f2bs(po) << 16);
                        *(u32*)&pW[mt * 16 + quad * 4 + r][nt * 16 + l15] = packed;
                    }
                }
            }
        }

    // ---- O = P @ V (A-frag from pW, B-frag from vT) ----
    f32x4 oacc[2][4];
    #pragma unroll
    for (int mt = 0; mt < 2; ++mt)
        #pragma unroll
        for (int nd = 0; nd < 4; ++nd)
            oacc[mt][nd] = (f32x4){0.f, 0.f, 0.f, 0.f};
    #pragma unroll
    for (int ks = 0; ks < 4; ++ks) {
        if (ks <= ksmax) {
            short8 pf0 = *(const short8*)&pW[l15     ][ks * 32 + quad * 8];
            short8 pf1 = *(const short8*)&pW[16 + l15][ks * 32 + quad * 8];
            #pragma unroll
            for (int nd = 0; nd < 4; ++nd) {
                short8 vf = *(const short8*)&vT[nd * 16 + l15][ks * 32 + quad * 8];
                oacc[0][nd] = __builtin_amdgcn_mfma_f32_16x16x32_bf16(pf0, vf, oacc[0][nd], 0, 0, 0);
                oacc[1][nd] = __builtin_amdgcn_mfma_f32_16x16x32_bf16(pf1, vf, oacc[1][nd], 0, 0, 0);
            }
        }
    }

    // ---- write out (pack col pairs via shfl, even l15 writes u32) ----
    #pragma unroll
    for (int mt = 0; mt < 2; ++mt)
        #pragma unroll
        for (int nd = 0; nd < 4; ++nd)
            #pragma unroll
            for (int r = 0; r < 4; ++r) {
                float ov = oacc[mt][nd][r] * ls[mt][r];
                float oo = __shfl_xor(ov, 1);
                if (wl) {
                    long long rowq = (long long)b * 128 + w * 32 + mt * 16 + quad * 4 + r;
                    u32 packed = (u32)f2bs(ov) | ((u32)f2bs(oo) << 16);
                    *(u32*)&out[rowq * 512 + h * 64 + nd * 16 + l15] = packed;
                }
            }
}

// ===========================================================================
// LayerNorm over 512, templated dtypes. In-place OK.
// ===========================================================================
template<typename TI, typename TO>
__global__ __launch_bounds__(256) void ln512_t(
    const TI* __restrict__ x, const float* __restrict__ g,
    const float* __restrict__ bt, TO* __restrict__ y, float eps)
{
    int row = blockIdx.x, tid = threadIdx.x;
    long long base = (long long)row * 512;
    float v0 = ldany(&x[base + tid]);
    float v1 = ldany(&x[base + 256 + tid]);
    float s = v0 + v1, ss = v0 * v0 + v1 * v1;
    #pragma unroll
    for (int o = 32; o >= 1; o >>= 1) { s += __shfl_xor(s, o); ss += __shfl_xor(ss, o); }
    __shared__ float red[2][4];
    int wave = tid >> 6, lane = tid & 63;
    if (lane == 0) { red[0][wave] = s; red[1][wave] = ss; }
    __syncthreads();
    s  = red[0][0] + red[0][1] + red[0][2] + red[0][3];
    ss = red[1][0] + red[1][1] + red[1][2] + red[1][3];
    float mean = s * (1.f / 512.f);
    float var = ss * (1.f / 512.f) - mean * mean;
    float rstd = rsqrtf(fmaxf(var, 0.f) + eps);
    float o0 = (v0 - mean) * rstd * g[tid]       + bt[tid];
    float o1 = (v1 - mean) * rstd * g[256 + tid] + bt[256 + tid];
    if constexpr (sizeof(TO) == 4) { y[base + tid] = o0; y[base + 256 + tid] = o1; }
    else { y[base + tid] = f2bs(o0); y[base + 256 + tid] = f2bs(o1); }
}

// ===========================================================================
// MoE expert attention: block = (expert e, batch b), thread = query s.
// Fuses the gate; writes geo[row, e*64+d] = gate_e(row) * eo_e[row,d].
// ===========================================================================
__global__ __launch_bounds__(128) void moe_attn_k(
    const float* __restrict__ qe,   // [3, B*S, 64]
    const float* __restrict__ ke,   // [3, B*R, 64]
    const float* __restrict__ ve,   // [3, B*R, 64]
    const float* __restrict__ xs,   // [B*S, 64] (for the gate)
    const float* __restrict__ Wg,   // [64,3]
    const float* __restrict__ bg,   // [3]
    float* __restrict__ geo)        // [B*S, 192]
{
    int e = blockIdx.x, b = blockIdx.y;
    int tid = threadIdx.x;
    __shared__ __align__(16) float kS[RR][64];
    __shared__ __align__(16) float vS[RR][64];

    {   // stage K/V tile for (e,b): 2048 floats each = 512 float4, coalesced
        const float4* ks = (const float4*)&ke[((long long)e * (BBt * RR) + (long long)b * RR) * 64];
        const float4* vs = (const float4*)&ve[((long long)e * (BBt * RR) + (long long)b * RR) * 64];
        float4* kd = (float4*)&kS[0][0];
        float4* vd = (float4*)&vS[0][0];
        #pragma unroll
        for (int t = 0; t < 4; ++t) {
            kd[tid + 128 * t] = ks[tid + 128 * t];
            vd[tid + 128 * t] = vs[tid + 128 * t];
        }
    }

    long long row = (long long)b * SS + tid;
    float q[64];
    {
        const float4* qp = (const float4*)&qe[((long long)e * (BBt * SS) + row) * 64];
        #pragma unroll
        for (int t = 0; t < 16; ++t) {
            float4 f = qp[t];
            q[4*t] = f.x; q[4*t+1] = f.y; q[4*t+2] = f.z; q[4*t+3] = f.w;
        }
    }

    // gate = softmax(xs_row @ Wg + bg)[e]
    float l0 = bg[0], l1 = bg[1], l2 = bg[2];
    {
        const float4* xr = (const float4*)&xs[row * 64];
        #pragma unroll
        for (int t = 0; t < 16; ++t) {
            float4 f = xr[t];
            float xv[4] = {f.x, f.y, f.z, f.w};
            #pragma unroll
            for (int u = 0; u < 4; ++u) {
                int j = 4 * t + u;
                l0 = fmaf(xv[u], Wg[j * 3 + 0], l0);
                l1 = fmaf(xv[u], Wg[j * 3 + 1], l1);
                l2 = fmaf(xv[u], Wg[j * 3 + 2], l2);
            }
        }
    }
    float mg = fmaxf(l0, fmaxf(l1, l2));
    float g0 = __expf(l0 - mg), g1 = __expf(l1 - mg), g2 = __expf(l2 - mg);
    float gate = (e == 0 ? g0 : (e == 1 ? g1 : g2)) / (g0 + g1 + g2);

    __syncthreads();

    // scores (two-pass softmax, all in registers)
    float s[RR];
    #pragma unroll
    for (int r = 0; r < RR; ++r) {
        float a0 = 0.f, a1 = 0.f, a2 = 0.f, a3 = 0.f;
        const float4* kr = (const float4*)&kS[r][0];
        #pragma unroll
        for (int t = 0; t < 16; ++t) {
            float4 f = kr[t];
            a0 = fmaf(q[4*t],   f.x, a0);
            a1 = fmaf(q[4*t+1], f.y, a1);
            a2 = fmaf(q[4*t+2], f.z, a2);
            a3 = fmaf(q[4*t+3], f.w, a3);
        }
        s[r] = ((a0 + a1) + (a2 + a3)) * 0.125f;   // 1/sqrt(64)
    }
    float m = s[0];
    #pragma unroll
    for (int r = 1; r < RR; ++r) m = fmaxf(m, s[r]);
    float l = 0.f;
    #pragma unroll
    for (int r = 0; r < RR; ++r) { s[r] = __expf(s[r] - m); l += s[r]; }
    float scale = gate / l;

    // PV
    float acc[64];
    #pragma unroll
    for (int d = 0; d < 64; ++d) acc[d] = 0.f;
    #pragma unroll
    for (int r = 0; r < RR; ++r) {
        float p = s[r];
        const float4* vr = (const float4*)&vS[r][0];
        #pragma unroll
        for (int t = 0; t < 16; ++t) {
            float4 f = vr[t];
            acc[4*t]   = fmaf(p, f.x, acc[4*t]);
            acc[4*t+1] = fmaf(p, f.y, acc[4*t+1]);
            acc[4*t+2] = fmaf(p, f.z, acc[4*t+2]);
            acc[4*t+3] = fmaf(p, f.w, acc[4*t+3]);
        }
    }
    float4* op = (float4*)&geo[row * 192 + e * 64];
    #pragma unroll
    for (int t = 0; t < 16; ++t) {
        float4 f;
        f.x = acc[4*t] * scale;   f.y = acc[4*t+1] * scale;
        f.z = acc[4*t+2] * scale; f.w = acc[4*t+3] * scale;
        op[t] = f;
    }
}

// ===========================================================================
// Small causal MHA on 64-dim priori (H=8, dh=8, S=128). qkv packed [B*S,192].
// ===========================================================================
__global__ __launch_bounds__(128) void attn_small_k(
    const float* __restrict__ qkv, float* __restrict__ out)
{
    int h = blockIdx.x, b = blockIdx.y;
    int tid = threadIdx.x;
    __shared__ float kS[SS][9], vS[SS][9];
    long long base = ((long long)b * SS + tid) * 192;
    #pragma unroll
    for (int d = 0; d < 8; ++d) {
        kS[tid][d] = qkv[base + 64 + h * 8 + d];
        vS[tid][d] = qkv[base + 128 + h * 8 + d];
    }
    float q[8];
    #pragma unroll
    for (int d = 0; d < 8; ++d)
        q[d] = qkv[base + h * 8 + d] * 0.35355339059327373f;
    __syncthreads();

    float m = -1e30f, l = 0.f, acc[8] = {};
    for (int j = 0; j <= tid; ++j) {
        float s = 0.f;
        #pragma unroll
        for (int d = 0; d < 8; ++d) s = fmaf(q[d], kS[j][d], s);
        float mn = fmaxf(m, s);
        float corr = __expf(m - mn);
        float p = __expf(s - mn);
        l = l * corr + p;
        #pragma unroll
        for (int d = 0; d < 8; ++d) acc[d] = fmaf(p, vS[j][d], acc[d] * corr);
        m = mn;
    }
    float inv = 1.f / l;
    #pragma unroll
    for (int d = 0; d < 8; ++d)
        out[((long long)b * SS + tid) * 64 + h * 8 + d] = acc[d] * inv;
}

__global__ __launch_bounds__(256) void ln64_k(
    const float* __restrict__ x, const float* __restrict__ g,
    const float* __restrict__ bt, float* __restrict__ y, int M)
{
    int wave = threadIdx.x >> 6, lane = threadIdx.x & 63;
    int row = blockIdx.x * 4 + wave;
    if (row >= M) return;
    long long base = (long long)row * 64;
    float v = x[base + lane];
    float s = v, ss = v * v;
    #pragma unroll
    for (int o = 32; o >= 1; o >>= 1) { s += __shfl_xor(s, o); ss += __shfl_xor(ss, o); }
    float mean = s * (1.f / 64.f);
    float var = ss * (1.f / 64.f) - mean * mean;
    float rstd = rsqrtf(fmaxf(var, 0.f) + 1e-5f);
    y[base + lane] = (v - mean) * rstd * g[lane] + bt[lane];
}

// ===========================================================================
extern "C" void kernel_launch(void* const* d_in, const int* in_sizes, int n_in,
                              void* d_out, int out_size, void* d_ws, size_t ws_size,
                              hipStream_t stream)
{
    (void)in_sizes; (void)n_in; (void)out_size; (void)ws_size;
    const float* hidden = (const float*)d_in[0];
    const float* tag    = (const float*)d_in[1];
    const float* feats  = (const float*)d_in[2];
    const float* refs   = (const float*)d_in[3];
    const float* W_moe  = (const float*)d_in[4];
    const float* b_moe  = (const float*)d_in[5];
    const float* Wg     = (const float*)d_in[6];
    const float* bg     = (const float*)d_in[7];
    const float* Wq_e   = (const float*)d_in[8];
    const float* Wk_e   = (const float*)d_in[9];
    const float* Wv_e   = (const float*)d_in[10];
    const float* Wo_e   = (const float*)d_in[11];
    const float* g_np   = (const float*)d_in[12];
    const float* b_np   = (const float*)d_in[13];
    const float* Wi_p   = (const float*)d_in[14];
    const float* bi_p   = (const float*)d_in[15];
    const float* Wo_p   = (const float*)d_in[16];
    const float* bo_p   = (const float*)d_in[17];
    const float* W_pe   = (const float*)d_in[18];
    const float* b_pe   = (const float*)d_in[19];
    const float* g_nh   = (const float*)d_in[20];
    const float* b_nh   = (const float*)d_in[21];
    const float* Wi_f   = (const float*)d_in[22];
    const float* bi_f   = (const float*)d_in[23];
    const float* Wo_f   = (const float*)d_in[24];
    const float* bo_f   = (const float*)d_in[25];
    const float* g_nfh  = (const float*)d_in[26];
    const float* b_nfh  = (const float*)d_in[27];
    const float* Wq_a   = (const float*)d_in[28];
    const float* bq_a   = (const float*)d_in[29];
    const float* Wk_a   = (const float*)d_in[30];
    const float* bk_a   = (const float*)d_in[31];
    const float* Wv_a   = (const float*)d_in[32];
    const float* bv_a   = (const float*)d_in[33];
    const float* Wd     = (const float*)d_in[34];
    const float* bd     = (const float*)d_in[35];
    const float* g_ln   = (const float*)d_in[36];
    const float* b_ln   = (const float*)d_in[37];
    float* out = (float*)d_out;
    char* ob = (char*)d_out;
    char* wb = (char*)d_ws;

    // bf16 slabs: ws = W0|W1 (16 MiB each); d_out doubles as O0|O1.
    u16* W0 = (u16*)(wb + 0LL * 16 * MB);
    u16* W1 = (u16*)(wb + 1LL * 16 * MB);
    u16* O0 = (u16*)(ob + 0LL * 16 * MB);
    u16* O1 = (u16*)(ob + 1LL * 16 * MB);

    // Stage A fp32 scratch: in d_out (lifetime-disjoint with O0/O1 use) and
    // in ws (o_qe under W0's slab, o_geo under W1's slab — both dead before
    // W0/W1 are first written).
    float* o_xs   = (float*)(ob + 0LL  * MB);
    float* o_ke   = (float*)(ob + 4LL  * MB);
    float* o_ve   = (float*)(ob + 7LL  * MB);
    float* o_pri  = (float*)(ob + 10LL * MB);
    float* o_np64 = (float*)(ob + 14LL * MB);
    float* o_qkv  = (float*)(ob + 18LL * MB);
    float* o_attp = (float*)(ob + 0LL  * MB);
    float* o_tmp  = (float*)(ob + 4LL  * MB);
    float* o_qe   = (float*)(wb + 0LL  * MB);   // [3,16384,64] = 12 MiB
    float* o_geo  = (float*)(wb + 16LL * MB);   // [16384,192]  = 12.6 MiB

    dim3 blk(256);
    const float* fnull = nullptr;
    float* f32null = nullptr;
    u16* u16null = nullptr;

    // ---- A: MoE priori ----
    gemm_bb<float, float, float><<<dim3(1, 128), blk, 0, stream>>>(       // xs
        tag, 512, 0, W_moe, fnull, 64, 0, b_moe, fnull, fnull, 0,
        o_xs, f32null, 64, 0, 512, 64, 0);
    gemm_bb<float, float, float><<<dim3(1, 32, 3), blk, 0, stream>>>(     // k_e|v_e fused
        refs, 512, 4096LL * 512, Wk_e, Wv_e, 64, 512LL * 64, fnull, fnull, fnull, 0,
        o_ke, o_ve, 64, 4096LL * 64, 512, 128, 64);
    gemm_bb<float, float, float><<<dim3(1, 128, 3), blk, 0, stream>>>(    // q_e
        o_xs, 64, 0, Wq_e, fnull, 64, 4096LL, fnull, fnull, fnull, 0,
        o_qe, f32null, 64, 16384LL * 64, 64, 64, 0);
    moe_attn_k<<<dim3(3, 128), dim3(128), 0, stream>>>(                   // geo = gate*eo
        o_qe, o_ke, o_ve, o_xs, Wg, bg, o_geo);
    gemm_bb<float, float, float><<<dim3(1, 128), blk, 0, stream>>>(       // priori = geo @ Wo_cat
        o_geo, 192, 0, Wo_e, fnull, 64, 0, fnull, fnull, fnull, 0,
        o_pri, f32null, 64, 0, 192, 64, 0);

    // ---- B: priori causal self-MHA + expansion to 512 ----
    ln64_k<<<dim3(4096), blk, 0, stream>>>(o_pri, g_np, b_np, o_np64, 16384);
    gemm_bb<float, float, float><<<dim3(2, 128), blk, 0, stream>>>(       // qkv_p
        o_np64, 64, 0, Wi_p, fnull, 192, 0, bi_p, fnull, fnull, 0,
        o_qkv, f32null, 192, 0, 64, 192, 0);
    attn_small_k<<<dim3(8, 128), dim3(128), 0, stream>>>(o_qkv, o_attp);
    gemm_bb<float, float, float><<<dim3(1, 128), blk, 0, stream>>>(       // tmp64 (+res priori)
        o_attp, 64, 0, Wo_p, fnull, 64, 0, bo_p, fnull, o_pri, 64,
        o_tmp, f32null, 64, 0, 64, 64, 0);
    gemm_bb<float, float, u16><<<dim3(4, 128), blk, 0, stream>>>(         // priori_e -> W0
        o_tmp, 64, 0, W_pe, fnull, 512, 0, b_pe, fnull, fnull, 0,
        W0, u16null, 512, 0, 64, 512, 0);

    // ---- C: fusion cross-MHA ----
    ln512_t<u16, u16><<<dim3(16384), blk, 0, stream>>>(W0, g_nh, b_nh, W0, 1e-5f); // npri
    gemm_bb<u16, float, u16><<<dim3(8, 128), blk, 0, stream>>>(           // Kf->O1 | Vf->W1 fused
        W0, 512, 0, Wi_f + 512, fnull, 1536, 0, bi_f + 512, fnull, fnull, 0,
        O1, W1, 512, 0, 512, 1024, 512);
    gemm_bb<float, float, u16><<<dim3(4, 128), blk, 0, stream>>>(         // Qf -> O0
        hidden, 512, 0, Wi_f, fnull, 1536, 0, bi_f, fnull, fnull, 0,
        O0, u16null, 512, 0, 512, 512, 0);
    attn_mfma_k<<<dim3(8, 128), dim3(256), 0, stream>>>(O0, O1, W1, W0, 128, 1);   // attn -> W0
    gemm_bb<u16, float, u16><<<dim3(4, 128), blk, 0, stream>>>(           // hidden2 -> O0
        W0, 512, 0, Wo_f, fnull, 512, 0, bo_f, fnull, hidden, 512,
        O0, u16null, 512, 0, 512, 512, 0);

    // ---- D: feat cross-attention ----
    ln512_t<u16, u16><<<dim3(16384), blk, 0, stream>>>(O0, g_nfh, b_nfh, O0, 1e-5f); // nh
    gemm_bb<u16, float, u16><<<dim3(4, 128), blk, 0, stream>>>(           // q_a -> O1
        O0, 512, 0, Wq_a, fnull, 512, 0, bq_a, fnull, fnull, 0,
        O1, u16null, 512, 0, 512, 512, 0);
    gemm_bb<float, float, u16><<<dim3(8, 84), blk, 0, stream>>>(          // k_a->W0 | v_a->W1 fused
        feats, 512, 0, Wk_a, Wv_a, 512, 0, bk_a, bv_a, fnull, 0,
        W0, W1, 512, 0, 512, 1024, 512);
    attn_mfma_k<<<dim3(8, 128), dim3(256), 0, stream>>>(O1, W0, W1, O1, 84, 0);    // ctx in-place
    gemm_bb<u16, u16, u16><<<dim3(4, 128), blk, 0, stream>>>(             // ctxd -> W0 (+res nh)
        O1, 512, 0, Wd, fnull, 512, 0, bd, fnull, O0, 512,
        W0, u16null, 512, 0, 512, 512, 0);

    // ---- E: final post-LN (eps=1e-12) -> fp32 d_out ----
    ln512_t<u16, float><<<dim3(16384), blk, 0, stream>>>(W0, g_ln, b_ln, out, 1e-12f);
}

// Round 6
// 1243.158 us; speedup vs baseline: 1.1009x; 1.1009x over previous
//
#include <hip/hip_runtime.h>
#include <hip/hip_bf16.h>

typedef unsigned short u16;
typedef unsigned int   u32;
typedef __attribute__((ext_vector_type(8))) short short8;   // 8 bf16 (4 VGPRs)
typedef __attribute__((ext_vector_type(4))) float f32x4;

#define BBt 128
#define SS 128
#define RR 32
#define NEx 3
#define MB (1024 * 1024)

static __device__ __forceinline__ float bs2f(u16 u){ return __uint_as_float(((u32)u) << 16); }
static __device__ __forceinline__ u16 f2bs(float x){
    u32 u = __float_as_uint(x);
    u += 0x7fff + ((u >> 16) & 1);          // RNE
    return (u16)(u >> 16);
}
static __device__ __forceinline__ u32 pkbf(float a, float b){   // pack 2 fp32 -> 2 bf16 (RNE)
    u32 r; asm("v_cvt_pk_bf16_f32 %0, %1, %2" : "=v"(r) : "v"(a), "v"(b)); return r;
}
static __device__ __forceinline__ float ldany(const float* p){ return *p; }
static __device__ __forceinline__ float ldany(const u16* p){ return bs2f(*p); }
// 8-byte-aligned short8 load (for 88B-stride LDS rows; no b128 alignment assumption)
static __device__ __forceinline__ short8 ld8(const u16* p){
    union { uint2 u[2]; short8 s; } x;
    x.u[0] = *(const uint2*)(p);
    x.u[1] = *(const uint2*)(p + 4);
    return x.s;
}

// ===========================================================================
// MFMA GEMM v3: C[M,N] = A[M,K] @ W[K,N] (+bias) (+Res), dual-output split.
// BM=128, BN=128, BK=32, 256 threads (4 waves 2x2). Two-barrier LDS-staged
// structure (proven r2) with two fixes:
//  - W staging reads are row-coalesced: each wave sweeps 64 consecutive
//    columns of one W row per load instr (256B contiguous), one k-octet/wave.
//  - LDS tiles padded to [128][44] (88B rows): B u32 staging writes 4-way
//    (was 8-way), A writes 2-way, frag reads ~2-way. Frag loads via uint2.
// W2/bias2/C2 split columns at Nsplit (fused K|V projections).
// Frag conventions (validated): A lane(l15,quad)=A[l15][quad*8+i];
// B lane(l15,quad)=W[quad*8+i][l15]; C/D col=l15, row=quad*4+reg.
// M % 128 == 0, K % 32 == 0, Ncols % 8 == 0. Batched via z.
// ===========================================================================
template<typename TA, typename TRes, typename TC>
__global__ __launch_bounds__(256) void gemm_v3(
    const TA* __restrict__ A, int lda, long long sA,
    const float* __restrict__ W, const float* __restrict__ W2, int ldw, long long sW,
    const float* __restrict__ bias, const float* __restrict__ bias2,
    const TRes* __restrict__ Res, int ldr,
    TC* __restrict__ C, TC* __restrict__ C2, int ldc, long long sC,
    int K, int Ncols, int Nsplit)
{
    int bz = blockIdx.z;
    A += (long long)bz * sA;
    W += (long long)bz * sW;
    if (W2) W2 += (long long)bz * sW;
    C += (long long)bz * sC;
    if (C2) C2 += (long long)bz * sC;

    __shared__ __align__(16) u16 As[128][44];
    __shared__ __align__(16) u16 Bs[128][44];

    int tid = threadIdx.x;
    long long row0 = (long long)blockIdx.y * 128;
    int col0 = blockIdx.x * 128;

    int wid = tid >> 6, lane = tid & 63;
    int wm = (wid >> 1) * 64, wn = (wid & 1) * 64;
    int l15 = lane & 15, quad = lane >> 4;

    f32x4 acc[4][4];
    #pragma unroll
    for (int i = 0; i < 4; ++i)
        #pragma unroll
        for (int j = 0; j < 4; ++j)
            acc[i][j] = (f32x4){0.f, 0.f, 0.f, 0.f};

    int ar = tid >> 1, ak = (tid & 1) * 16;        // A stage map
    int bn = tid & 63, bkg = (tid >> 6) * 8;       // B stage map: wave owns k-octet

    for (int kt = 0; kt < K; kt += 32) {
        {   // ---- stage A tile [128,32] -> bf16 ----
            const TA* src = A + (row0 + ar) * lda + kt + ak;
            if constexpr (sizeof(TA) == 4) {
                float4 f0 = *(const float4*)(src);
                float4 f1 = *(const float4*)(src + 4);
                float4 f2 = *(const float4*)(src + 8);
                float4 f3 = *(const float4*)(src + 12);
                u32 t[8] = {pkbf(f0.x,f0.y), pkbf(f0.z,f0.w), pkbf(f1.x,f1.y), pkbf(f1.z,f1.w),
                            pkbf(f2.x,f2.y), pkbf(f2.z,f2.w), pkbf(f3.x,f3.y), pkbf(f3.z,f3.w)};
                *(uint2*)&As[ar][ak]      = *(uint2*)&t[0];
                *(uint2*)&As[ar][ak + 4]  = *(uint2*)&t[2];
                *(uint2*)&As[ar][ak + 8]  = *(uint2*)&t[4];
                *(uint2*)&As[ar][ak + 12] = *(uint2*)&t[6];
            } else {
                uint4 v0 = *(const uint4*)(src);
                uint4 v1 = *(const uint4*)(src + 8);
                *(uint2*)&As[ar][ak]      = make_uint2(v0.x, v0.y);
                *(uint2*)&As[ar][ak + 4]  = make_uint2(v0.z, v0.w);
                *(uint2*)&As[ar][ak + 8]  = make_uint2(v1.x, v1.y);
                *(uint2*)&As[ar][ak + 12] = make_uint2(v1.z, v1.w);
            }
        }
        {   // ---- stage W tile [32,128] -> Bs[n][k], row-coalesced reads ----
            #pragma unroll
            for (int p = 0; p < 2; ++p) {
                int n = p * 64 + bn;
                int coln = col0 + n;
                const float* wsrc = W; int wc = coln;
                if (W2 && coln >= Nsplit) { wsrc = W2; wc = coln - Nsplit; }
                bool ok = (coln < Ncols);
                const float* pw = wsrc + (long long)(kt + bkg) * ldw + wc;
                #pragma unroll
                for (int j = 0; j < 4; ++j) {
                    float w0 = 0.f, w1 = 0.f;
                    if (ok) {
                        w0 = pw[(long long)(2 * j) * ldw];
                        w1 = pw[(long long)(2 * j + 1) * ldw];
                    }
                    *(u32*)&Bs[n][bkg + 2 * j] = pkbf(w0, w1);
                }
            }
        }
        __syncthreads();

        short8 af[4], bfr[4];
        #pragma unroll
        for (int mt = 0; mt < 4; ++mt)
            af[mt] = ld8(&As[wm + mt * 16 + l15][quad * 8]);
        #pragma unroll
        for (int nt = 0; nt < 4; ++nt)
            bfr[nt] = ld8(&Bs[wn + nt * 16 + l15][quad * 8]);
        #pragma unroll
        for (int mt = 0; mt < 4; ++mt)
            #pragma unroll
            for (int nt = 0; nt < 4; ++nt)
                acc[mt][nt] = __builtin_amdgcn_mfma_f32_16x16x32_bf16(
                    af[mt], bfr[nt], acc[mt][nt], 0, 0, 0);
        __syncthreads();
    }

    // ---- epilogue: C/D layout col=lane&15, row=quad*4+reg ----
    #pragma unroll
    for (int mt = 0; mt < 4; ++mt) {
        #pragma unroll
        for (int r = 0; r < 4; ++r) {
            long long row = row0 + wm + mt * 16 + quad * 4 + r;
            #pragma unroll
            for (int nt = 0; nt < 4; ++nt) {
                int col = col0 + wn + nt * 16 + l15;
                if (col >= Ncols) continue;
                float v = acc[mt][nt][r];
                if (bias2 && col >= Nsplit) v += bias2[col - Nsplit];
                else if (bias)              v += bias[col];
                if (Res) v += ldany(&Res[row * ldr + col]);
                TC* dst = (C2 && col >= Nsplit) ? (C2 + row * ldc + (col - Nsplit))
                                                : (C  + row * ldc + col);
                if constexpr (sizeof(TC) == 4) *dst = v;
                else                           *dst = f2bs(v);
            }
        }
    }
}

// ===========================================================================
// MFMA flash-less attention, bf16 in/out. Block per (head h, batch b).
// 4 waves x 32 query rows. Q[128,64], K[L,64], V[L,64] per (b,h), L <= 128.
// S = Q @ K^T : kS natural [kv][d]; O = P @ V : vT transposed [d][kv].
// P round-trips through per-wave LDS (aliased over dead kS; one barrier).
// Causal waves skip tiles: nt <= 2w+1, ks <= w.
// out may alias Q (Q fully register-resident before any store).
// ===========================================================================
__global__ __launch_bounds__(256) void attn_mfma_k(
    const u16* __restrict__ Q, const u16* __restrict__ K,
    const u16* __restrict__ V, u16* __restrict__ out,
    int L, int causal)
{
    int h = blockIdx.x, b = blockIdx.y;
    int tid = threadIdx.x;
    int w = tid >> 6, lane = tid & 63;
    int l15 = lane & 15, quad = lane >> 4;

    int NTP = (L + 15) >> 4;          // padded kv tiles (6 or 8)
    int Lp  = NTP * 16;               // 96 or 128
    int ntmax = causal ? (2 * w + 1) : (NTP - 1);        // wave-uniform
    int ksmax = causal ? w : (((L + 31) >> 5) - 1);      // wave-uniform

    __shared__ __align__(16) u16 vT[64][136];            // V^T [d][kv], 17408 B
    __shared__ __align__(16) u16 pool[4][32][136];       // pS (aliases kS), 34816 B
    u16 (*kS)[72] = (u16(*)[72])&pool[0][0][0];          // [128][72] = 18432 B

    // ---- stage K natural [kv][d] (zero-pad rows >= L) ----
    for (int i = tid; i < Lp * 8; i += 256) {
        int r = i >> 3, c8 = i & 7;
        uint4 val = {0u, 0u, 0u, 0u};
        if (r < L) val = *(const uint4*)&K[((long long)b * L + r) * 512 + h * 64 + c8 * 8];
        *(uint4*)&kS[r][c8 * 8] = val;
    }
    // ---- stage V transposed [d][kv] (zero-pad kv >= L) ----
    for (int i = tid; i < 512; i += 256) {       // dg = i>>6 in 0..7, kp = i&63
        int kp = i & 63, dg = i >> 6;
        int kv0 = kp * 2;
        if (kv0 < Lp) {
            uint4 r0 = {0u,0u,0u,0u}, r1 = {0u,0u,0u,0u};
            if (kv0 < L)     r0 = *(const uint4*)&V[((long long)b * L + kv0    ) * 512 + h * 64 + dg * 8];
            if (kv0 + 1 < L) r1 = *(const uint4*)&V[((long long)b * L + kv0 + 1) * 512 + h * 64 + dg * 8];
            u32 w0[4] = {r0.x, r0.y, r0.z, r0.w};
            u32 w1[4] = {r1.x, r1.y, r1.z, r1.w};
            #pragma unroll
            for (int j = 0; j < 4; ++j) {
                *(u32*)&vT[dg * 8 + 2 * j    ][kv0] = (w0[j] & 0xffffu) | (w1[j] << 16);
                *(u32*)&vT[dg * 8 + 2 * j + 1][kv0] = (w0[j] >> 16) | (w1[j] & 0xffff0000u);
            }
        }
    }

    // ---- Q fragments direct from global (A-frag layout) ----
    short8 qf[2][2];
    #pragma unroll
    for (int mt = 0; mt < 2; ++mt)
        #pragma unroll
        for (int ks = 0; ks < 2; ++ks)
            qf[mt][ks] = *(const short8*)&Q[((long long)b * 128 + w * 32 + mt * 16 + l15) * 512
                                            + h * 64 + ks * 32 + quad * 8];
    __syncthreads();

    // ---- S = Q @ K^T (tiles guarded by wave-uniform ntmax) ----
    f32x4 sacc[2][8];
    #pragma unroll
    for (int mt = 0; mt < 2; ++mt)
        #pragma unroll
        for (int nt = 0; nt < 8; ++nt)
            sacc[mt][nt] = (f32x4){0.f, 0.f, 0.f, 0.f};
    #pragma unroll
    for (int nt = 0; nt < 8; ++nt) {
        if (nt <= ntmax) {
            short8 kf0 = *(const short8*)&kS[nt * 16 + l15][quad * 8];
            short8 kf1 = *(const short8*)&kS[nt * 16 + l15][32 + quad * 8];
            #pragma unroll
            for (int mt = 0; mt < 2; ++mt) {
                sacc[mt][nt] = __builtin_amdgcn_mfma_f32_16x16x32_bf16(qf[mt][0], kf0, sacc[mt][nt], 0, 0, 0);
                sacc[mt][nt] = __builtin_amdgcn_mfma_f32_16x16x32_bf16(qf[mt][1], kf1, sacc[mt][nt], 0, 0, 0);
            }
        }
    }

    // ---- softmax over rows (cols = l15 lanes x nt tiles); scale 1/8 folded ----
    float pm[2][4], ls[2][4];
    #pragma unroll
    for (int mt = 0; mt < 2; ++mt) {
        #pragma unroll
        for (int r = 0; r < 4; ++r) pm[mt][r] = -1e30f;
        #pragma unroll
        for (int nt = 0; nt < 8; ++nt) {
            if (nt <= ntmax) {
                int col = nt * 16 + l15;
                #pragma unroll
                for (int r = 0; r < 4; ++r) {
                    int rowq = w * 32 + mt * 16 + quad * 4 + r;
                    bool bad = (col >= L) || (causal && col > rowq);
                    float sv = bad ? -1e30f : sacc[mt][nt][r];
                    sacc[mt][nt][r] = sv;
                    pm[mt][r] = fmaxf(pm[mt][r], sv);
                }
            }
        }
        #pragma unroll
        for (int r = 0; r < 4; ++r) {
            float mx = pm[mt][r];
            #pragma unroll
            for (int o = 1; o <= 8; o <<= 1) mx = fmaxf(mx, __shfl_xor(mx, o));
            pm[mt][r] = mx * 0.125f;           // scaled max
            ls[mt][r] = 0.f;
        }
        #pragma unroll
        for (int nt = 0; nt < 8; ++nt) {
            if (nt <= ntmax) {
                #pragma unroll
                for (int r = 0; r < 4; ++r) {
                    float p = __expf(fmaf(sacc[mt][nt][r], 0.125f, -pm[mt][r]));
                    sacc[mt][nt][r] = p;
                    ls[mt][r] += p;
                }
            }
        }
        #pragma unroll
        for (int r = 0; r < 4; ++r) {
            float sm = ls[mt][r];
            #pragma unroll
            for (int o = 1; o <= 8; o <<= 1) sm += __shfl_xor(sm, o);
            ls[mt][r] = 1.f / sm;
        }
    }

    __syncthreads();   // kS dead -> reuse as per-wave P tiles

    // ---- P -> bf16 -> per-wave LDS (pack col pairs via shfl, even l15 writes) ----
    u16 (*pW)[136] = (u16(*)[136])&pool[w][0][0];
    bool wl = (l15 & 1) == 0;
    #pragma unroll
    for (int mt = 0; mt < 2; ++mt)
        #pragma unroll
        for (int nt = 0; nt < 8; ++nt) {
            if (nt <= ntmax) {
                #pragma unroll
                for (int r = 0; r < 4; ++r) {
                    float pv = sacc[mt][nt][r];
                    float po = __shfl_xor(pv, 1);
                    if (wl) {
                        u32 packed = (u32)f2bs(pv) | ((u32)f2bs(po) << 16);
                        *(u32*)&pW[mt * 16 + quad * 4 + r][nt * 16 + l15] = packed;
                    }
                }
            }
        }

    // ---- O = P @ V (A-frag from pW, B-frag from vT) ----
    f32x4 oacc[2][4];
    #pragma unroll
    for (int mt = 0; mt < 2; ++mt)
        #pragma unroll
        for (int nd = 0; nd < 4; ++nd)
            oacc[mt][nd] = (f32x4){0.f, 0.f, 0.f, 0.f};
    #pragma unroll
    for (int ks = 0; ks < 4; ++ks) {
        if (ks <= ksmax) {
            short8 pf0 = *(const short8*)&pW[l15     ][ks * 32 + quad * 8];
            short8 pf1 = *(const short8*)&pW[16 + l15][ks * 32 + quad * 8];
            #pragma unroll
            for (int nd = 0; nd < 4; ++nd) {
                short8 vf = *(const short8*)&vT[nd * 16 + l15][ks * 32 + quad * 8];
                oacc[0][nd] = __builtin_amdgcn_mfma_f32_16x16x32_bf16(pf0, vf, oacc[0][nd], 0, 0, 0);
                oacc[1][nd] = __builtin_amdgcn_mfma_f32_16x16x32_bf16(pf1, vf, oacc[1][nd], 0, 0, 0);
            }
        }
    }

    // ---- write out (pack col pairs via shfl, even l15 writes u32) ----
    #pragma unroll
    for (int mt = 0; mt < 2; ++mt)
        #pragma unroll
        for (int nd = 0; nd < 4; ++nd)
            #pragma unroll
            for (int r = 0; r < 4; ++r) {
                float ov = oacc[mt][nd][r] * ls[mt][r];
                float oo = __shfl_xor(ov, 1);
                if (wl) {
                    long long rowq = (long long)b * 128 + w * 32 + mt * 16 + quad * 4 + r;
                    u32 packed = (u32)f2bs(ov) | ((u32)f2bs(oo) << 16);
                    *(u32*)&out[rowq * 512 + h * 64 + nd * 16 + l15] = packed;
                }
            }
}

// ===========================================================================
// LayerNorm over 512, templated dtypes. In-place OK.
// ===========================================================================
template<typename TI, typename TO>
__global__ __launch_bounds__(256) void ln512_t(
    const TI* __restrict__ x, const float* __restrict__ g,
    const float* __restrict__ bt, TO* __restrict__ y, float eps)
{
    int row = blockIdx.x, tid = threadIdx.x;
    long long base = (long long)row * 512;
    float v0 = ldany(&x[base + tid]);
    float v1 = ldany(&x[base + 256 + tid]);
    float s = v0 + v1, ss = v0 * v0 + v1 * v1;
    #pragma unroll
    for (int o = 32; o >= 1; o >>= 1) { s += __shfl_xor(s, o); ss += __shfl_xor(ss, o); }
    __shared__ float red[2][4];
    int wave = tid >> 6, lane = tid & 63;
    if (lane == 0) { red[0][wave] = s; red[1][wave] = ss; }
    __syncthreads();
    s  = red[0][0] + red[0][1] + red[0][2] + red[0][3];
    ss = red[1][0] + red[1][1] + red[1][2] + red[1][3];
    float mean = s * (1.f / 512.f);
    float var = ss * (1.f / 512.f) - mean * mean;
    float rstd = rsqrtf(fmaxf(var, 0.f) + eps);
    float o0 = (v0 - mean) * rstd * g[tid]       + bt[tid];
    float o1 = (v1 - mean) * rstd * g[256 + tid] + bt[256 + tid];
    if constexpr (sizeof(TO) == 4) { y[base + tid] = o0; y[base + 256 + tid] = o1; }
    else { y[base + tid] = f2bs(o0); y[base + 256 + tid] = f2bs(o1); }
}

// ===========================================================================
// MoE expert attention: block = (expert e, batch b), thread = query s.
// Fuses the gate; writes geo[row, e*64+d] = gate_e(row) * eo_e[row,d].
// ===========================================================================
__global__ __launch_bounds__(128) void moe_attn_k(
    const float* __restrict__ qe,   // [3, B*S, 64]
    const float* __restrict__ ke,   // [3, B*R, 64]
    const float* __restrict__ ve,   // [3, B*R, 64]
    const float* __restrict__ xs,   // [B*S, 64] (for the gate)
    const float* __restrict__ Wg,   // [64,3]
    const float* __restrict__ bg,   // [3]
    float* __restrict__ geo)        // [B*S, 192]
{
    int e = blockIdx.x, b = blockIdx.y;
    int tid = threadIdx.x;
    __shared__ __align__(16) float kS[RR][64];
    __shared__ __align__(16) float vS[RR][64];

    {   // stage K/V tile for (e,b): 2048 floats each = 512 float4, coalesced
        const float4* ks = (const float4*)&ke[((long long)e * (BBt * RR) + (long long)b * RR) * 64];
        const float4* vs = (const float4*)&ve[((long long)e * (BBt * RR) + (long long)b * RR) * 64];
        float4* kd = (float4*)&kS[0][0];
        float4* vd = (float4*)&vS[0][0];
        #pragma unroll
        for (int t = 0; t < 4; ++t) {
            kd[tid + 128 * t] = ks[tid + 128 * t];
            vd[tid + 128 * t] = vs[tid + 128 * t];
        }
    }

    long long row = (long long)b * SS + tid;
    float q[64];
    {
        const float4* qp = (const float4*)&qe[((long long)e * (BBt * SS) + row) * 64];
        #pragma unroll
        for (int t = 0; t < 16; ++t) {
            float4 f = qp[t];
            q[4*t] = f.x; q[4*t+1] = f.y; q[4*t+2] = f.z; q[4*t+3] = f.w;
        }
    }

    // gate = softmax(xs_row @ Wg + bg)[e]
    float l0 = bg[0], l1 = bg[1], l2 = bg[2];
    {
        const float4* xr = (const float4*)&xs[row * 64];
        #pragma unroll
        for (int t = 0; t < 16; ++t) {
            float4 f = xr[t];
            float xv[4] = {f.x, f.y, f.z, f.w};
            #pragma unroll
            for (int u = 0; u < 4; ++u) {
                int j = 4 * t + u;
                l0 = fmaf(xv[u], Wg[j * 3 + 0], l0);
                l1 = fmaf(xv[u], Wg[j * 3 + 1], l1);
                l2 = fmaf(xv[u], Wg[j * 3 + 2], l2);
            }
        }
    }
    float mg = fmaxf(l0, fmaxf(l1, l2));
    float g0 = __expf(l0 - mg), g1 = __expf(l1 - mg), g2 = __expf(l2 - mg);
    float gate = (e == 0 ? g0 : (e == 1 ? g1 : g2)) / (g0 + g1 + g2);

    __syncthreads();

    // scores (two-pass softmax, all in registers)
    float s[RR];
    #pragma unroll
    for (int r = 0; r < RR; ++r) {
        float a0 = 0.f, a1 = 0.f, a2 = 0.f, a3 = 0.f;
        const float4* kr = (const float4*)&kS[r][0];
        #pragma unroll
        for (int t = 0; t < 16; ++t) {
            float4 f = kr[t];
            a0 = fmaf(q[4*t],   f.x, a0);
            a1 = fmaf(q[4*t+1], f.y, a1);
            a2 = fmaf(q[4*t+2], f.z, a2);
            a3 = fmaf(q[4*t+3], f.w, a3);
        }
        s[r] = ((a0 + a1) + (a2 + a3)) * 0.125f;   // 1/sqrt(64)
    }
    float m = s[0];
    #pragma unroll
    for (int r = 1; r < RR; ++r) m = fmaxf(m, s[r]);
    float l = 0.f;
    #pragma unroll
    for (int r = 0; r < RR; ++r) { s[r] = __expf(s[r] - m); l += s[r]; }
    float scale = gate / l;

    // PV
    float acc[64];
    #pragma unroll
    for (int d = 0; d < 64; ++d) acc[d] = 0.f;
    #pragma unroll
    for (int r = 0; r < RR; ++r) {
        float p = s[r];
        const float4* vr = (const float4*)&vS[r][0];
        #pragma unroll
        for (int t = 0; t < 16; ++t) {
            float4 f = vr[t];
            acc[4*t]   = fmaf(p, f.x, acc[4*t]);
            acc[4*t+1] = fmaf(p, f.y, acc[4*t+1]);
            acc[4*t+2] = fmaf(p, f.z, acc[4*t+2]);
            acc[4*t+3] = fmaf(p, f.w, acc[4*t+3]);
        }
    }
    float4* op = (float4*)&geo[row * 192 + e * 64];
    #pragma unroll
    for (int t = 0; t < 16; ++t) {
        float4 f;
        f.x = acc[4*t] * scale;   f.y = acc[4*t+1] * scale;
        f.z = acc[4*t+2] * scale; f.w = acc[4*t+3] * scale;
        op[t] = f;
    }
}

// ===========================================================================
// Small causal MHA on 64-dim priori (H=8, dh=8, S=128). qkv packed [B*S,192].
// ===========================================================================
__global__ __launch_bounds__(128) void attn_small_k(
    const float* __restrict__ qkv, float* __restrict__ out)
{
    int h = blockIdx.x, b = blockIdx.y;
    int tid = threadIdx.x;
    __shared__ float kS[SS][9], vS[SS][9];
    long long base = ((long long)b * SS + tid) * 192;
    #pragma unroll
    for (int d = 0; d < 8; ++d) {
        kS[tid][d] = qkv[base + 64 + h * 8 + d];
        vS[tid][d] = qkv[base + 128 + h * 8 + d];
    }
    float q[8];
    #pragma unroll
    for (int d = 0; d < 8; ++d)
        q[d] = qkv[base + h * 8 + d] * 0.35355339059327373f;
    __syncthreads();

    float m = -1e30f, l = 0.f, acc[8] = {};
    for (int j = 0; j <= tid; ++j) {
        float s = 0.f;
        #pragma unroll
        for (int d = 0; d < 8; ++d) s = fmaf(q[d], kS[j][d], s);
        float mn = fmaxf(m, s);
        float corr = __expf(m - mn);
        float p = __expf(s - mn);
        l = l * corr + p;
        #pragma unroll
        for (int d = 0; d < 8; ++d) acc[d] = fmaf(p, vS[j][d], acc[d] * corr);
        m = mn;
    }
    float inv = 1.f / l;
    #pragma unroll
    for (int d = 0; d < 8; ++d)
        out[((long long)b * SS + tid) * 64 + h * 8 + d] = acc[d] * inv;
}

__global__ __launch_bounds__(256) void ln64_k(
    const float* __restrict__ x, const float* __restrict__ g,
    const float* __restrict__ bt, float* __restrict__ y, int M)
{
    int wave = threadIdx.x >> 6, lane = threadIdx.x & 63;
    int row = blockIdx.x * 4 + wave;
    if (row >= M) return;
    long long base = (long long)row * 64;
    float v = x[base + lane];
    float s = v, ss = v * v;
    #pragma unroll
    for (int o = 32; o >= 1; o >>= 1) { s += __shfl_xor(s, o); ss += __shfl_xor(ss, o); }
    float mean = s * (1.f / 64.f);
    float var = ss * (1.f / 64.f) - mean * mean;
    float rstd = rsqrtf(fmaxf(var, 0.f) + 1e-5f);
    y[base + lane] = (v - mean) * rstd * g[lane] + bt[lane];
}

// ===========================================================================
extern "C" void kernel_launch(void* const* d_in, const int* in_sizes, int n_in,
                              void* d_out, int out_size, void* d_ws, size_t ws_size,
                              hipStream_t stream)
{
    (void)in_sizes; (void)n_in; (void)out_size; (void)ws_size;
    const float* hidden = (const float*)d_in[0];
    const float* tag    = (const float*)d_in[1];
    const float* feats  = (const float*)d_in[2];
    const float* refs   = (const float*)d_in[3];
    const float* W_moe  = (const float*)d_in[4];
    const float* b_moe  = (const float*)d_in[5];
    const float* Wg     = (const float*)d_in[6];
    const float* bg     = (const float*)d_in[7];
    const float* Wq_e   = (const float*)d_in[8];
    const float* Wk_e   = (const float*)d_in[9];
    const float* Wv_e   = (const float*)d_in[10];
    const float* Wo_e   = (const float*)d_in[11];
    const float* g_np   = (const float*)d_in[12];
    const float* b_np   = (const float*)d_in[13];
    const float* Wi_p   = (const float*)d_in[14];
    const float* bi_p   = (const float*)d_in[15];
    const float* Wo_p   = (const float*)d_in[16];
    const float* bo_p   = (const float*)d_in[17];
    const float* W_pe   = (const float*)d_in[18];
    const float* b_pe   = (const float*)d_in[19];
    const float* g_nh   = (const float*)d_in[20];
    const float* b_nh   = (const float*)d_in[21];
    const float* Wi_f   = (const float*)d_in[22];
    const float* bi_f   = (const float*)d_in[23];
    const float* Wo_f   = (const float*)d_in[24];
    const float* bo_f   = (const float*)d_in[25];
    const float* g_nfh  = (const float*)d_in[26];
    const float* b_nfh  = (const float*)d_in[27];
    const float* Wq_a   = (const float*)d_in[28];
    const float* bq_a   = (const float*)d_in[29];
    const float* Wk_a   = (const float*)d_in[30];
    const float* bk_a   = (const float*)d_in[31];
    const float* Wv_a   = (const float*)d_in[32];
    const float* bv_a   = (const float*)d_in[33];
    const float* Wd     = (const float*)d_in[34];
    const float* bd     = (const float*)d_in[35];
    const float* g_ln   = (const float*)d_in[36];
    const float* b_ln   = (const float*)d_in[37];
    float* out = (float*)d_out;
    char* ob = (char*)d_out;
    char* wb = (char*)d_ws;

    // bf16 slabs: ws = W0|W1 (16 MiB each); d_out doubles as O0|O1.
    u16* W0 = (u16*)(wb + 0LL * 16 * MB);
    u16* W1 = (u16*)(wb + 1LL * 16 * MB);
    u16* O0 = (u16*)(ob + 0LL * 16 * MB);
    u16* O1 = (u16*)(ob + 1LL * 16 * MB);

    // Stage A fp32 scratch: in d_out (lifetime-disjoint with O0/O1 use) and
    // in ws (o_qe under W0's slab, o_geo under W1's slab — both dead before
    // W0/W1 are first written).
    float* o_xs   = (float*)(ob + 0LL  * MB);
    float* o_ke   = (float*)(ob + 4LL  * MB);
    float* o_ve   = (float*)(ob + 7LL  * MB);
    float* o_pri  = (float*)(ob + 10LL * MB);
    float* o_np64 = (float*)(ob + 14LL * MB);
    float* o_qkv  = (float*)(ob + 18LL * MB);
    float* o_attp = (float*)(ob + 0LL  * MB);
    float* o_tmp  = (float*)(ob + 4LL  * MB);
    float* o_qe   = (float*)(wb + 0LL  * MB);   // [3,16384,64] = 12 MiB
    float* o_geo  = (float*)(wb + 16LL * MB);   // [16384,192]  = 12.6 MiB

    dim3 blk(256);
    const float* fnull = nullptr;
    float* f32null = nullptr;
    u16* u16null = nullptr;

    // ---- A: MoE priori ----
    gemm_v3<float, float, float><<<dim3(1, 128), blk, 0, stream>>>(       // xs
        tag, 512, 0, W_moe, fnull, 64, 0, b_moe, fnull, fnull, 0,
        o_xs, f32null, 64, 0, 512, 64, 0);
    gemm_v3<float, float, float><<<dim3(1, 32, 3), blk, 0, stream>>>(     // k_e|v_e fused
        refs, 512, 4096LL * 512, Wk_e, Wv_e, 64, 512LL * 64, fnull, fnull, fnull, 0,
        o_ke, o_ve, 64, 4096LL * 64, 512, 128, 64);
    gemm_v3<float, float, float><<<dim3(1, 128, 3), blk, 0, stream>>>(    // q_e
        o_xs, 64, 0, Wq_e, fnull, 64, 4096LL, fnull, fnull, fnull, 0,
        o_qe, f32null, 64, 16384LL * 64, 64, 64, 0);
    moe_attn_k<<<dim3(3, 128), dim3(128), 0, stream>>>(                   // geo = gate*eo
        o_qe, o_ke, o_ve, o_xs, Wg, bg, o_geo);
    gemm_v3<float, float, float><<<dim3(1, 128), blk, 0, stream>>>(       // priori = geo @ Wo_cat
        o_geo, 192, 0, Wo_e, fnull, 64, 0, fnull, fnull, fnull, 0,
        o_pri, f32null, 64, 0, 192, 64, 0);

    // ---- B: priori causal self-MHA + expansion to 512 ----
    ln64_k<<<dim3(4096), blk, 0, stream>>>(o_pri, g_np, b_np, o_np64, 16384);
    gemm_v3<float, float, float><<<dim3(2, 128), blk, 0, stream>>>(       // qkv_p
        o_np64, 64, 0, Wi_p, fnull, 192, 0, bi_p, fnull, fnull, 0,
        o_qkv, f32null, 192, 0, 64, 192, 0);
    attn_small_k<<<dim3(8, 128), dim3(128), 0, stream>>>(o_qkv, o_attp);
    gemm_v3<float, float, float><<<dim3(1, 128), blk, 0, stream>>>(       // tmp64 (+res priori)
        o_attp, 64, 0, Wo_p, fnull, 64, 0, bo_p, fnull, o_pri, 64,
        o_tmp, f32null, 64, 0, 64, 64, 0);
    gemm_v3<float, float, u16><<<dim3(4, 128), blk, 0, stream>>>(         // priori_e -> W0
        o_tmp, 64, 0, W_pe, fnull, 512, 0, b_pe, fnull, fnull, 0,
        W0, u16null, 512, 0, 64, 512, 0);

    // ---- C: fusion cross-MHA ----
    ln512_t<u16, u16><<<dim3(16384), blk, 0, stream>>>(W0, g_nh, b_nh, W0, 1e-5f); // npri
    gemm_v3<u16, float, u16><<<dim3(8, 128), blk, 0, stream>>>(           // Kf->O1 | Vf->W1 fused
        W0, 512, 0, Wi_f + 512, fnull, 1536, 0, bi_f + 512, fnull, fnull, 0,
        O1, W1, 512, 0, 512, 1024, 512);
    gemm_v3<float, float, u16><<<dim3(4, 128), blk, 0, stream>>>(         // Qf -> O0
        hidden, 512, 0, Wi_f, fnull, 1536, 0, bi_f, fnull, fnull, 0,
        O0, u16null, 512, 0, 512, 512, 0);
    attn_mfma_k<<<dim3(8, 128), dim3(256), 0, stream>>>(O0, O1, W1, W0, 128, 1);   // attn -> W0
    gemm_v3<u16, float, u16><<<dim3(4, 128), blk, 0, stream>>>(           // hidden2 -> O0
        W0, 512, 0, Wo_f, fnull, 512, 0, bo_f, fnull, hidden, 512,
        O0, u16null, 512, 0, 512, 512, 0);

    // ---- D: feat cross-attention ----
    ln512_t<u16, u16><<<dim3(16384), blk, 0, stream>>>(O0, g_nfh, b_nfh, O0, 1e-5f); // nh
    gemm_v3<u16, float, u16><<<dim3(4, 128), blk, 0, stream>>>(           // q_a -> O1
        O0, 512, 0, Wq_a, fnull, 512, 0, bq_a, fnull, fnull, 0,
        O1, u16null, 512, 0, 512, 512, 0);
    gemm_v3<float, float, u16><<<dim3(8, 84), blk, 0, stream>>>(          // k_a->W0 | v_a->W1 fused
        feats, 512, 0, Wk_a, Wv_a, 512, 0, bk_a, bv_a, fnull, 0,
        W0, W1, 512, 0, 512, 1024, 512);
    attn_mfma_k<<<dim3(8, 128), dim3(256), 0, stream>>>(O1, W0, W1, O1, 84, 0);    // ctx in-place
    gemm_v3<u16, u16, u16><<<dim3(4, 128), blk, 0, stream>>>(             // ctxd -> W0 (+res nh)
        O1, 512, 0, Wd, fnull, 512, 0, bd, fnull, O0, 512,
        W0, u16null, 512, 0, 512, 512, 0);

    // ---- E: final post-LN (eps=1e-12) -> fp32 d_out ----
    ln512_t<u16, float><<<dim3(16384), blk, 0, stream>>>(W0, g_ln, b_ln, out, 1e-12f);
}

// Round 7
// 887.537 us; speedup vs baseline: 1.5420x; 1.4007x over previous
//
#include <hip/hip_runtime.h>
#include <hip/hip_bf16.h>

typedef unsigned short u16;
typedef unsigned int   u32;
typedef __attribute__((ext_vector_type(8))) short short8;   // 8 bf16 (4 VGPRs)
typedef __attribute__((ext_vector_type(4))) float f32x4;

#define BBt 128
#define SS 128
#define RR 32
#define NEx 3
#define MB (1024 * 1024)

static __device__ __forceinline__ float bs2f(u16 u){ return __uint_as_float(((u32)u) << 16); }
static __device__ __forceinline__ u16 f2bs(float x){
    u32 u = __float_as_uint(x);
    u += 0x7fff + ((u >> 16) & 1);          // RNE
    return (u16)(u >> 16);
}
static __device__ __forceinline__ u32 pkbf(float a, float b){   // pack 2 fp32 -> 2 bf16 (RNE)
    u32 r; asm("v_cvt_pk_bf16_f32 %0, %1, %2" : "=v"(r) : "v"(a), "v"(b)); return r;
}
static __device__ __forceinline__ float ldany(const float* p){ return *p; }
static __device__ __forceinline__ float ldany(const u16* p){ return bs2f(*p); }

// ===========================================================================
// Weight transpose+convert: dst[n][k] (bf16, ld=ldd) = src[k][n] (fp32, ld=lds_).
// Grid (N/32, K/32, z). One-shot per weight; runs once per forward.
// ===========================================================================
__global__ __launch_bounds__(256) void tr_bf(
    const float* __restrict__ src, int lds_, long long sSrc,
    u16* __restrict__ dst, long long sDst, int ldd)
{
    int z = blockIdx.z;
    src += (long long)z * sSrc;
    dst += (long long)z * sDst;
    int n0 = blockIdx.x * 32, k0 = blockIdx.y * 32;
    __shared__ u16 t[32][33];
    int c = threadIdx.x & 31, r0 = threadIdx.x >> 5;
    #pragma unroll
    for (int i = 0; i < 4; ++i) {
        int r = r0 + i * 8;
        t[r][c] = f2bs(src[(long long)(k0 + r) * lds_ + n0 + c]);
    }
    __syncthreads();
    int rr = threadIdx.x >> 3, kk = (threadIdx.x & 7) * 4;
    u16 o[4] = { t[kk][rr], t[kk+1][rr], t[kk+2][rr], t[kk+3][rr] };
    *(uint2*)&dst[(long long)(n0 + rr) * ldd + k0 + kk] = *(uint2*)o;
}

// ===========================================================================
// MFMA GEMM (r3-proven): C[M,N] = A[M,K] @ W[K,N] (+bias) (+Res).
// BM=128, BN=128 (cols >= Ncols masked), BK=32, 256 threads (4 waves 2x2).
// A: fp32 or bf16. W: fp32 row-major (transposed to LDS). C: fp32 or bf16.
// ===========================================================================
template<typename TA, typename TRes, typename TC>
__global__ __launch_bounds__(256) void gemm_mfma(
    const TA* __restrict__ A, int lda, long long sA,
    const float* __restrict__ W, int ldw, long long sW,
    const float* __restrict__ bias,
    const TRes* __restrict__ Res, int ldr,
    TC* __restrict__ C, int ldc, long long sC,
    int K, int Ncols)
{
    int bz = blockIdx.z;
    A += (long long)bz * sA;
    W += (long long)bz * sW;
    C += (long long)bz * sC;

    __shared__ __align__(16) u16 As[128][40];   // [m][k]
    __shared__ __align__(16) u16 Bs[128][40];   // [n][k] (W transposed)

    int tid = threadIdx.x;
    long long row0 = (long long)blockIdx.y * 128;
    int col0 = blockIdx.x * 128;

    int wid = tid >> 6, lane = tid & 63;
    int wm = (wid >> 1) * 64, wn = (wid & 1) * 64;
    int l15 = lane & 15, quad = lane >> 4;

    f32x4 acc[4][4];
    #pragma unroll
    for (int i = 0; i < 4; ++i)
        #pragma unroll
        for (int j = 0; j < 4; ++j)
            acc[i][j] = (f32x4){0.f, 0.f, 0.f, 0.f};

    int ar = tid >> 1, ak = (tid & 1) * 16;
    int bk0 = (tid & 15) * 2, bn0 = (tid >> 4) * 8;

    for (int kt = 0; kt < K; kt += 32) {
        {   // ---- stage A tile [128,32] -> bf16 ----
            const TA* src = A + (row0 + ar) * lda + kt + ak;
            if constexpr (sizeof(TA) == 4) {
                u16 tmp[16];
                #pragma unroll
                for (int t = 0; t < 16; t += 4) {
                    float4 f = *(const float4*)(src + t);
                    tmp[t] = f2bs(f.x); tmp[t+1] = f2bs(f.y);
                    tmp[t+2] = f2bs(f.z); tmp[t+3] = f2bs(f.w);
                }
                *(uint4*)&As[ar][ak]     = *(const uint4*)&tmp[0];
                *(uint4*)&As[ar][ak + 8] = *(const uint4*)&tmp[8];
            } else {
                *(uint4*)&As[ar][ak]     = *(const uint4*)(src);
                *(uint4*)&As[ar][ak + 8] = *(const uint4*)(src + 8);
            }
        }
        {   // ---- stage W tile [32,128] transposed -> Bs[n][k], N-guarded ----
            if (col0 + bn0 < Ncols) {
                const float* w0 = W + (long long)(kt + bk0) * ldw + col0 + bn0;
                const float* w1 = w0 + ldw;
                float r0[8], r1[8];
                *(float4*)&r0[0] = *(const float4*)(w0);
                *(float4*)&r0[4] = *(const float4*)(w0 + 4);
                *(float4*)&r1[0] = *(const float4*)(w1);
                *(float4*)&r1[4] = *(const float4*)(w1 + 4);
                #pragma unroll
                for (int i = 0; i < 8; ++i) {
                    u32 packed = (u32)f2bs(r0[i]) | ((u32)f2bs(r1[i]) << 16);
                    *(u32*)&Bs[bn0 + i][bk0] = packed;
                }
            } else {
                #pragma unroll
                for (int i = 0; i < 8; ++i)
                    *(u32*)&Bs[bn0 + i][bk0] = 0u;
            }
        }
        __syncthreads();

        short8 af[4], bfr[4];
        #pragma unroll
        for (int mt = 0; mt < 4; ++mt)
            af[mt] = *(const short8*)&As[wm + mt * 16 + l15][quad * 8];
        #pragma unroll
        for (int nt = 0; nt < 4; ++nt)
            bfr[nt] = *(const short8*)&Bs[wn + nt * 16 + l15][quad * 8];
        #pragma unroll
        for (int mt = 0; mt < 4; ++mt)
            #pragma unroll
            for (int nt = 0; nt < 4; ++nt)
                acc[mt][nt] = __builtin_amdgcn_mfma_f32_16x16x32_bf16(
                    af[mt], bfr[nt], acc[mt][nt], 0, 0, 0);
        __syncthreads();
    }

    // ---- epilogue: C/D layout col=lane&15, row=quad*4+reg ----
    #pragma unroll
    for (int mt = 0; mt < 4; ++mt) {
        #pragma unroll
        for (int r = 0; r < 4; ++r) {
            long long row = row0 + wm + mt * 16 + quad * 4 + r;
            #pragma unroll
            for (int nt = 0; nt < 4; ++nt) {
                int col = col0 + wn + nt * 16 + l15;
                if (col >= Ncols) continue;
                float v = acc[mt][nt][r];
                if (bias) v += bias[col];
                if (Res)  v += ldany(&Res[row * ldr + col]);
                if constexpr (sizeof(TC) == 4) C[row * ldc + col] = v;
                else                           C[row * ldc + col] = f2bs(v);
            }
        }
    }
}

// ===========================================================================
// MFMA GEMM v5: same structure as gemm_mfma, but B comes from a PRE-TRANSPOSED
// bf16 weight WT[Ncols][K] (row-major): B staging is a straight coalesced
// uint4 row copy (no f2bs, no strided reads, no transpose in the hot loop).
// Optional C2 column split at Nsplit (fused K|V expert projections).
// ===========================================================================
template<typename TA, typename TRes, typename TC>
__global__ __launch_bounds__(256) void gemm_v5(
    const TA* __restrict__ A, int lda, long long sA,
    const u16* __restrict__ WT, long long sW,
    const float* __restrict__ bias, const float* __restrict__ bias2,
    const TRes* __restrict__ Res, int ldr,
    TC* __restrict__ C, TC* __restrict__ C2, int ldc, long long sC,
    int K, int Ncols, int Nsplit)
{
    int bz = blockIdx.z;
    A += (long long)bz * sA;
    WT += (long long)bz * sW;
    C += (long long)bz * sC;
    if (C2) C2 += (long long)bz * sC;

    __shared__ __align__(16) u16 As[128][40];
    __shared__ __align__(16) u16 Bs[128][40];

    int tid = threadIdx.x;
    long long row0 = (long long)blockIdx.y * 128;
    int col0 = blockIdx.x * 128;

    int wid = tid >> 6, lane = tid & 63;
    int wm = (wid >> 1) * 64, wn = (wid & 1) * 64;
    int l15 = lane & 15, quad = lane >> 4;

    f32x4 acc[4][4];
    #pragma unroll
    for (int i = 0; i < 4; ++i)
        #pragma unroll
        for (int j = 0; j < 4; ++j)
            acc[i][j] = (f32x4){0.f, 0.f, 0.f, 0.f};

    int ar = tid >> 1, ak = (tid & 1) * 16;

    for (int kt = 0; kt < K; kt += 32) {
        {   // ---- stage A tile [128,32] -> bf16 ----
            const TA* src = A + (row0 + ar) * lda + kt + ak;
            if constexpr (sizeof(TA) == 4) {
                float4 f0 = *(const float4*)(src);
                float4 f1 = *(const float4*)(src + 4);
                float4 f2 = *(const float4*)(src + 8);
                float4 f3 = *(const float4*)(src + 12);
                u32 t[8] = {pkbf(f0.x,f0.y), pkbf(f0.z,f0.w), pkbf(f1.x,f1.y), pkbf(f1.z,f1.w),
                            pkbf(f2.x,f2.y), pkbf(f2.z,f2.w), pkbf(f3.x,f3.y), pkbf(f3.z,f3.w)};
                *(uint4*)&As[ar][ak]     = *(uint4*)&t[0];
                *(uint4*)&As[ar][ak + 8] = *(uint4*)&t[4];
            } else {
                *(uint4*)&As[ar][ak]     = *(const uint4*)(src);
                *(uint4*)&As[ar][ak + 8] = *(const uint4*)(src + 8);
            }
        }
        {   // ---- stage B tile: plain row copy from WT[n][k] ----
            int nr = col0 + ar;
            if (nr < Ncols) {
                const u16* ws = WT + (long long)nr * K + kt + ak;
                *(uint4*)&Bs[ar][ak]     = *(const uint4*)(ws);
                *(uint4*)&Bs[ar][ak + 8] = *(const uint4*)(ws + 8);
            } else {
                uint4 z = {0u, 0u, 0u, 0u};
                *(uint4*)&Bs[ar][ak] = z;
                *(uint4*)&Bs[ar][ak + 8] = z;
            }
        }
        __syncthreads();

        short8 af[4], bfr[4];
        #pragma unroll
        for (int mt = 0; mt < 4; ++mt)
            af[mt] = *(const short8*)&As[wm + mt * 16 + l15][quad * 8];
        #pragma unroll
        for (int nt = 0; nt < 4; ++nt)
            bfr[nt] = *(const short8*)&Bs[wn + nt * 16 + l15][quad * 8];
        #pragma unroll
        for (int mt = 0; mt < 4; ++mt)
            #pragma unroll
            for (int nt = 0; nt < 4; ++nt)
                acc[mt][nt] = __builtin_amdgcn_mfma_f32_16x16x32_bf16(
                    af[mt], bfr[nt], acc[mt][nt], 0, 0, 0);
        __syncthreads();
    }

    // ---- epilogue: C/D layout col=lane&15, row=quad*4+reg; C2 split ----
    #pragma unroll
    for (int mt = 0; mt < 4; ++mt) {
        #pragma unroll
        for (int r = 0; r < 4; ++r) {
            long long row = row0 + wm + mt * 16 + quad * 4 + r;
            #pragma unroll
            for (int nt = 0; nt < 4; ++nt) {
                int col = col0 + wn + nt * 16 + l15;
                if (col >= Ncols) continue;
                float v = acc[mt][nt][r];
                if (bias2 && col >= Nsplit) v += bias2[col - Nsplit];
                else if (bias)              v += bias[col];
                if (Res) v += ldany(&Res[row * ldr + col]);
                TC* dst = (C2 && col >= Nsplit) ? (C2 + row * ldc + (col - Nsplit))
                                                : (C  + row * ldc + col);
                if constexpr (sizeof(TC) == 4) *dst = v;
                else                           *dst = f2bs(v);
            }
        }
    }
}

// ===========================================================================
// MFMA flash-less attention, bf16 in/out. Block per (head h, batch b).
// 4 waves x 32 query rows. out may alias Q.
// ===========================================================================
__global__ __launch_bounds__(256) void attn_mfma_k(
    const u16* __restrict__ Q, const u16* __restrict__ K,
    const u16* __restrict__ V, u16* __restrict__ out,
    int L, int causal)
{
    int h = blockIdx.x, b = blockIdx.y;
    int tid = threadIdx.x;
    int w = tid >> 6, lane = tid & 63;
    int l15 = lane & 15, quad = lane >> 4;

    int NTP = (L + 15) >> 4;          // padded kv tiles (6 or 8)
    int Lp  = NTP * 16;               // 96 or 128
    int ntmax = causal ? (2 * w + 1) : (NTP - 1);        // wave-uniform
    int ksmax = causal ? w : (((L + 31) >> 5) - 1);      // wave-uniform

    __shared__ __align__(16) u16 vT[64][136];            // V^T [d][kv], 17408 B
    __shared__ __align__(16) u16 pool[4][32][136];       // pS (aliases kS), 34816 B
    u16 (*kS)[72] = (u16(*)[72])&pool[0][0][0];          // [128][72] = 18432 B

    // ---- stage K natural [kv][d] (zero-pad rows >= L) ----
    for (int i = tid; i < Lp * 8; i += 256) {
        int r = i >> 3, c8 = i & 7;
        uint4 val = {0u, 0u, 0u, 0u};
        if (r < L) val = *(const uint4*)&K[((long long)b * L + r) * 512 + h * 64 + c8 * 8];
        *(uint4*)&kS[r][c8 * 8] = val;
    }
    // ---- stage V transposed [d][kv] (zero-pad kv >= L) ----
    for (int i = tid; i < 512; i += 256) {       // dg = i>>6 in 0..7, kp = i&63
        int kp = i & 63, dg = i >> 6;
        int kv0 = kp * 2;
        if (kv0 < Lp) {
            uint4 r0 = {0u,0u,0u,0u}, r1 = {0u,0u,0u,0u};
            if (kv0 < L)     r0 = *(const uint4*)&V[((long long)b * L + kv0    ) * 512 + h * 64 + dg * 8];
            if (kv0 + 1 < L) r1 = *(const uint4*)&V[((long long)b * L + kv0 + 1) * 512 + h * 64 + dg * 8];
            u32 w0[4] = {r0.x, r0.y, r0.z, r0.w};
            u32 w1[4] = {r1.x, r1.y, r1.z, r1.w};
            #pragma unroll
            for (int j = 0; j < 4; ++j) {
                *(u32*)&vT[dg * 8 + 2 * j    ][kv0] = (w0[j] & 0xffffu) | (w1[j] << 16);
                *(u32*)&vT[dg * 8 + 2 * j + 1][kv0] = (w0[j] >> 16) | (w1[j] & 0xffff0000u);
            }
        }
    }

    // ---- Q fragments direct from global (A-frag layout) ----
    short8 qf[2][2];
    #pragma unroll
    for (int mt = 0; mt < 2; ++mt)
        #pragma unroll
        for (int ks = 0; ks < 2; ++ks)
            qf[mt][ks] = *(const short8*)&Q[((long long)b * 128 + w * 32 + mt * 16 + l15) * 512
                                            + h * 64 + ks * 32 + quad * 8];
    __syncthreads();

    // ---- S = Q @ K^T (tiles guarded by wave-uniform ntmax) ----
    f32x4 sacc[2][8];
    #pragma unroll
    for (int mt = 0; mt < 2; ++mt)
        #pragma unroll
        for (int nt = 0; nt < 8; ++nt)
            sacc[mt][nt] = (f32x4){0.f, 0.f, 0.f, 0.f};
    #pragma unroll
    for (int nt = 0; nt < 8; ++nt) {
        if (nt <= ntmax) {
            short8 kf0 = *(const short8*)&kS[nt * 16 + l15][quad * 8];
            short8 kf1 = *(const short8*)&kS[nt * 16 + l15][32 + quad * 8];
            #pragma unroll
            for (int mt = 0; mt < 2; ++mt) {
                sacc[mt][nt] = __builtin_amdgcn_mfma_f32_16x16x32_bf16(qf[mt][0], kf0, sacc[mt][nt], 0, 0, 0);
                sacc[mt][nt] = __builtin_amdgcn_mfma_f32_16x16x32_bf16(qf[mt][1], kf1, sacc[mt][nt], 0, 0, 0);
            }
        }
    }

    // ---- softmax over rows (cols = l15 lanes x nt tiles); scale 1/8 folded ----
    float pm[2][4], ls[2][4];
    #pragma unroll
    for (int mt = 0; mt < 2; ++mt) {
        #pragma unroll
        for (int r = 0; r < 4; ++r) pm[mt][r] = -1e30f;
        #pragma unroll
        for (int nt = 0; nt < 8; ++nt) {
            if (nt <= ntmax) {
                int col = nt * 16 + l15;
                #pragma unroll
                for (int r = 0; r < 4; ++r) {
                    int rowq = w * 32 + mt * 16 + quad * 4 + r;
                    bool bad = (col >= L) || (causal && col > rowq);
                    float sv = bad ? -1e30f : sacc[mt][nt][r];
                    sacc[mt][nt][r] = sv;
                    pm[mt][r] = fmaxf(pm[mt][r], sv);
                }
            }
        }
        #pragma unroll
        for (int r = 0; r < 4; ++r) {
            float mx = pm[mt][r];
            #pragma unroll
            for (int o = 1; o <= 8; o <<= 1) mx = fmaxf(mx, __shfl_xor(mx, o));
            pm[mt][r] = mx * 0.125f;           // scaled max
            ls[mt][r] = 0.f;
        }
        #pragma unroll
        for (int nt = 0; nt < 8; ++nt) {
            if (nt <= ntmax) {
                #pragma unroll
                for (int r = 0; r < 4; ++r) {
                    float p = __expf(fmaf(sacc[mt][nt][r], 0.125f, -pm[mt][r]));
                    sacc[mt][nt][r] = p;
                    ls[mt][r] += p;
                }
            }
        }
        #pragma unroll
        for (int r = 0; r < 4; ++r) {
            float sm = ls[mt][r];
            #pragma unroll
            for (int o = 1; o <= 8; o <<= 1) sm += __shfl_xor(sm, o);
            ls[mt][r] = 1.f / sm;
        }
    }

    __syncthreads();   // kS dead -> reuse as per-wave P tiles

    // ---- P -> bf16 -> per-wave LDS (pack col pairs via shfl, even l15 writes) ----
    u16 (*pW)[136] = (u16(*)[136])&pool[w][0][0];
    bool wl = (l15 & 1) == 0;
    #pragma unroll
    for (int mt = 0; mt < 2; ++mt)
        #pragma unroll
        for (int nt = 0; nt < 8; ++nt) {
            if (nt <= ntmax) {
                #pragma unroll
                for (int r = 0; r < 4; ++r) {
                    float pv = sacc[mt][nt][r];
                    float po = __shfl_xor(pv, 1);
                    if (wl) {
                        u32 packed = (u32)f2bs(pv) | ((u32)f2bs(po) << 16);
                        *(u32*)&pW[mt * 16 + quad * 4 + r][nt * 16 + l15] = packed;
                    }
                }
            }
        }

    // ---- O = P @ V (A-frag from pW, B-frag from vT) ----
    f32x4 oacc[2][4];
    #pragma unroll
    for (int mt = 0; mt < 2; ++mt)
        #pragma unroll
        for (int nd = 0; nd < 4; ++nd)
            oacc[mt][nd] = (f32x4){0.f, 0.f, 0.f, 0.f};
    #pragma unroll
    for (int ks = 0; ks < 4; ++ks) {
        if (ks <= ksmax) {
            short8 pf0 = *(const short8*)&pW[l15     ][ks * 32 + quad * 8];
            short8 pf1 = *(const short8*)&pW[16 + l15][ks * 32 + quad * 8];
            #pragma unroll
            for (int nd = 0; nd < 4; ++nd) {
                short8 vf = *(const short8*)&vT[nd * 16 + l15][ks * 32 + quad * 8];
                oacc[0][nd] = __builtin_amdgcn_mfma_f32_16x16x32_bf16(pf0, vf, oacc[0][nd], 0, 0, 0);
                oacc[1][nd] = __builtin_amdgcn_mfma_f32_16x16x32_bf16(pf1, vf, oacc[1][nd], 0, 0, 0);
            }
        }
    }

    // ---- write out (pack col pairs via shfl, even l15 writes u32) ----
    #pragma unroll
    for (int mt = 0; mt < 2; ++mt)
        #pragma unroll
        for (int nd = 0; nd < 4; ++nd)
            #pragma unroll
            for (int r = 0; r < 4; ++r) {
                float ov = oacc[mt][nd][r] * ls[mt][r];
                float oo = __shfl_xor(ov, 1);
                if (wl) {
                    long long rowq = (long long)b * 128 + w * 32 + mt * 16 + quad * 4 + r;
                    u32 packed = (u32)f2bs(ov) | ((u32)f2bs(oo) << 16);
                    *(u32*)&out[rowq * 512 + h * 64 + nd * 16 + l15] = packed;
                }
            }
}

// ===========================================================================
// LayerNorm over 512, templated dtypes. In-place OK.
// ===========================================================================
template<typename TI, typename TO>
__global__ __launch_bounds__(256) void ln512_t(
    const TI* __restrict__ x, const float* __restrict__ g,
    const float* __restrict__ bt, TO* __restrict__ y, float eps)
{
    int row = blockIdx.x, tid = threadIdx.x;
    long long base = (long long)row * 512;
    float v0 = ldany(&x[base + tid]);
    float v1 = ldany(&x[base + 256 + tid]);
    float s = v0 + v1, ss = v0 * v0 + v1 * v1;
    #pragma unroll
    for (int o = 32; o >= 1; o >>= 1) { s += __shfl_xor(s, o); ss += __shfl_xor(ss, o); }
    __shared__ float red[2][4];
    int wave = tid >> 6, lane = tid & 63;
    if (lane == 0) { red[0][wave] = s; red[1][wave] = ss; }
    __syncthreads();
    s  = red[0][0] + red[0][1] + red[0][2] + red[0][3];
    ss = red[1][0] + red[1][1] + red[1][2] + red[1][3];
    float mean = s * (1.f / 512.f);
    float var = ss * (1.f / 512.f) - mean * mean;
    float rstd = rsqrtf(fmaxf(var, 0.f) + eps);
    float o0 = (v0 - mean) * rstd * g[tid]       + bt[tid];
    float o1 = (v1 - mean) * rstd * g[256 + tid] + bt[256 + tid];
    if constexpr (sizeof(TO) == 4) { y[base + tid] = o0; y[base + 256 + tid] = o1; }
    else { y[base + tid] = f2bs(o0); y[base + 256 + tid] = f2bs(o1); }
}

// ===========================================================================
// MoE expert attention: block = (expert e, batch b), thread = query s.
// Fuses the gate; writes geo[row, e*64+d] = gate_e(row) * eo_e[row,d].
// ===========================================================================
__global__ __launch_bounds__(128) void moe_attn_k(
    const float* __restrict__ qe,   // [3, B*S, 64]
    const float* __restrict__ ke,   // [3, B*R, 64]
    const float* __restrict__ ve,   // [3, B*R, 64]
    const float* __restrict__ xs,   // [B*S, 64] (for the gate)
    const float* __restrict__ Wg,   // [64,3]
    const float* __restrict__ bg,   // [3]
    float* __restrict__ geo)        // [B*S, 192]
{
    int e = blockIdx.x, b = blockIdx.y;
    int tid = threadIdx.x;
    __shared__ __align__(16) float kS[RR][64];
    __shared__ __align__(16) float vS[RR][64];

    {   // stage K/V tile for (e,b): 2048 floats each = 512 float4, coalesced
        const float4* ks = (const float4*)&ke[((long long)e * (BBt * RR) + (long long)b * RR) * 64];
        const float4* vs = (const float4*)&ve[((long long)e * (BBt * RR) + (long long)b * RR) * 64];
        float4* kd = (float4*)&kS[0][0];
        float4* vd = (float4*)&vS[0][0];
        #pragma unroll
        for (int t = 0; t < 4; ++t) {
            kd[tid + 128 * t] = ks[tid + 128 * t];
            vd[tid + 128 * t] = vs[tid + 128 * t];
        }
    }

    long long row = (long long)b * SS + tid;
    float q[64];
    {
        const float4* qp = (const float4*)&qe[((long long)e * (BBt * SS) + row) * 64];
        #pragma unroll
        for (int t = 0; t < 16; ++t) {
            float4 f = qp[t];
            q[4*t] = f.x; q[4*t+1] = f.y; q[4*t+2] = f.z; q[4*t+3] = f.w;
        }
    }

    // gate = softmax(xs_row @ Wg + bg)[e]
    float l0 = bg[0], l1 = bg[1], l2 = bg[2];
    {
        const float4* xr = (const float4*)&xs[row * 64];
        #pragma unroll
        for (int t = 0; t < 16; ++t) {
            float4 f = xr[t];
            float xv[4] = {f.x, f.y, f.z, f.w};
            #pragma unroll
            for (int u = 0; u < 4; ++u) {
                int j = 4 * t + u;
                l0 = fmaf(xv[u], Wg[j * 3 + 0], l0);
                l1 = fmaf(xv[u], Wg[j * 3 + 1], l1);
                l2 = fmaf(xv[u], Wg[j * 3 + 2], l2);
            }
        }
    }
    float mg = fmaxf(l0, fmaxf(l1, l2));
    float g0 = __expf(l0 - mg), g1 = __expf(l1 - mg), g2 = __expf(l2 - mg);
    float gate = (e == 0 ? g0 : (e == 1 ? g1 : g2)) / (g0 + g1 + g2);

    __syncthreads();

    // scores (two-pass softmax, all in registers)
    float s[RR];
    #pragma unroll
    for (int r = 0; r < RR; ++r) {
        float a0 = 0.f, a1 = 0.f, a2 = 0.f, a3 = 0.f;
        const float4* kr = (const float4*)&kS[r][0];
        #pragma unroll
        for (int t = 0; t < 16; ++t) {
            float4 f = kr[t];
            a0 = fmaf(q[4*t],   f.x, a0);
            a1 = fmaf(q[4*t+1], f.y, a1);
            a2 = fmaf(q[4*t+2], f.z, a2);
            a3 = fmaf(q[4*t+3], f.w, a3);
        }
        s[r] = ((a0 + a1) + (a2 + a3)) * 0.125f;   // 1/sqrt(64)
    }
    float m = s[0];
    #pragma unroll
    for (int r = 1; r < RR; ++r) m = fmaxf(m, s[r]);
    float l = 0.f;
    #pragma unroll
    for (int r = 0; r < RR; ++r) { s[r] = __expf(s[r] - m); l += s[r]; }
    float scale = gate / l;

    // PV
    float acc[64];
    #pragma unroll
    for (int d = 0; d < 64; ++d) acc[d] = 0.f;
    #pragma unroll
    for (int r = 0; r < RR; ++r) {
        float p = s[r];
        const float4* vr = (const float4*)&vS[r][0];
        #pragma unroll
        for (int t = 0; t < 16; ++t) {
            float4 f = vr[t];
            acc[4*t]   = fmaf(p, f.x, acc[4*t]);
            acc[4*t+1] = fmaf(p, f.y, acc[4*t+1]);
            acc[4*t+2] = fmaf(p, f.z, acc[4*t+2]);
            acc[4*t+3] = fmaf(p, f.w, acc[4*t+3]);
        }
    }
    float4* op = (float4*)&geo[row * 192 + e * 64];
    #pragma unroll
    for (int t = 0; t < 16; ++t) {
        float4 f;
        f.x = acc[4*t] * scale;   f.y = acc[4*t+1] * scale;
        f.z = acc[4*t+2] * scale; f.w = acc[4*t+3] * scale;
        op[t] = f;
    }
}

// ===========================================================================
// Small causal MHA on 64-dim priori (H=8, dh=8, S=128). qkv packed [B*S,192].
// ===========================================================================
__global__ __launch_bounds__(128) void attn_small_k(
    const float* __restrict__ qkv, float* __restrict__ out)
{
    int h = blockIdx.x, b = blockIdx.y;
    int tid = threadIdx.x;
    __shared__ float kS[SS][9], vS[SS][9];
    long long base = ((long long)b * SS + tid) * 192;
    #pragma unroll
    for (int d = 0; d < 8; ++d) {
        kS[tid][d] = qkv[base + 64 + h * 8 + d];
        vS[tid][d] = qkv[base + 128 + h * 8 + d];
    }
    float q[8];
    #pragma unroll
    for (int d = 0; d < 8; ++d)
        q[d] = qkv[base + h * 8 + d] * 0.35355339059327373f;
    __syncthreads();

    float m = -1e30f, l = 0.f, acc[8] = {};
    for (int j = 0; j <= tid; ++j) {
        float s = 0.f;
        #pragma unroll
        for (int d = 0; d < 8; ++d) s = fmaf(q[d], kS[j][d], s);
        float mn = fmaxf(m, s);
        float corr = __expf(m - mn);
        float p = __expf(s - mn);
        l = l * corr + p;
        #pragma unroll
        for (int d = 0; d < 8; ++d) acc[d] = fmaf(p, vS[j][d], acc[d] * corr);
        m = mn;
    }
    float inv = 1.f / l;
    #pragma unroll
    for (int d = 0; d < 8; ++d)
        out[((long long)b * SS + tid) * 64 + h * 8 + d] = acc[d] * inv;
}

__global__ __launch_bounds__(256) void ln64_k(
    const float* __restrict__ x, const float* __restrict__ g,
    const float* __restrict__ bt, float* __restrict__ y, int M)
{
    int wave = threadIdx.x >> 6, lane = threadIdx.x & 63;
    int row = blockIdx.x * 4 + wave;
    if (row >= M) return;
    long long base = (long long)row * 64;
    float v = x[base + lane];
    float s = v, ss = v * v;
    #pragma unroll
    for (int o = 32; o >= 1; o >>= 1) { s += __shfl_xor(s, o); ss += __shfl_xor(ss, o); }
    float mean = s * (1.f / 64.f);
    float var = ss * (1.f / 64.f) - mean * mean;
    float rstd = rsqrtf(fmaxf(var, 0.f) + 1e-5f);
    y[base + lane] = (v - mean) * rstd * g[lane] + bt[lane];
}

// ===========================================================================
extern "C" void kernel_launch(void* const* d_in, const int* in_sizes, int n_in,
                              void* d_out, int out_size, void* d_ws, size_t ws_size,
                              hipStream_t stream)
{
    (void)in_sizes; (void)n_in; (void)out_size; (void)ws_size;
    const float* hidden = (const float*)d_in[0];
    const float* tag    = (const float*)d_in[1];
    const float* feats  = (const float*)d_in[2];
    const float* refs   = (const float*)d_in[3];
    const float* W_moe  = (const float*)d_in[4];
    const float* b_moe  = (const float*)d_in[5];
    const float* Wg     = (const float*)d_in[6];
    const float* bg     = (const float*)d_in[7];
    const float* Wq_e   = (const float*)d_in[8];
    const float* Wk_e   = (const float*)d_in[9];
    const float* Wv_e   = (const float*)d_in[10];
    const float* Wo_e   = (const float*)d_in[11];
    const float* g_np   = (const float*)d_in[12];
    const float* b_np   = (const float*)d_in[13];
    const float* Wi_p   = (const float*)d_in[14];
    const float* bi_p   = (const float*)d_in[15];
    const float* Wo_p   = (const float*)d_in[16];
    const float* bo_p   = (const float*)d_in[17];
    const float* W_pe   = (const float*)d_in[18];
    const float* b_pe   = (const float*)d_in[19];
    const float* g_nh   = (const float*)d_in[20];
    const float* b_nh   = (const float*)d_in[21];
    const float* Wi_f   = (const float*)d_in[22];
    const float* bi_f   = (const float*)d_in[23];
    const float* Wo_f   = (const float*)d_in[24];
    const float* bo_f   = (const float*)d_in[25];
    const float* g_nfh  = (const float*)d_in[26];
    const float* b_nfh  = (const float*)d_in[27];
    const float* Wq_a   = (const float*)d_in[28];
    const float* bq_a   = (const float*)d_in[29];
    const float* Wk_a   = (const float*)d_in[30];
    const float* bk_a   = (const float*)d_in[31];
    const float* Wv_a   = (const float*)d_in[32];
    const float* bv_a   = (const float*)d_in[33];
    const float* Wd     = (const float*)d_in[34];
    const float* bd     = (const float*)d_in[35];
    const float* g_ln   = (const float*)d_in[36];
    const float* b_ln   = (const float*)d_in[37];
    float* out = (float*)d_out;
    char* ob = (char*)d_out;
    char* wb = (char*)d_ws;

    // bf16 slabs: ws = W0|W1 (16 MiB each); d_out doubles as O0|O1.
    u16* W0 = (u16*)(wb + 0LL * 16 * MB);
    u16* W1 = (u16*)(wb + 1LL * 16 * MB);
    u16* O0 = (u16*)(ob + 0LL * 16 * MB);
    u16* O1 = (u16*)(ob + 1LL * 16 * MB);

    // fp32 scratch (stage A/B) in lifetime-dead regions (stream-serialized):
    float* o_xs   = (float*)(ob + 0LL  * MB);
    float* o_ke   = (float*)(ob + 4LL  * MB);
    float* o_ve   = (float*)(ob + 7LL  * MB);
    float* o_pri  = (float*)(ob + 10LL * MB);
    float* o_np64 = (float*)(ob + 14LL * MB);
    float* o_qkv  = (float*)(ob + 18LL * MB);
    float* o_attp = (float*)(ob + 0LL  * MB);
    float* o_tmp  = (float*)(ob + 4LL  * MB);
    float* o_qe   = (float*)(wb + 0LL  * MB);   // [3,16384,64] = 12 MiB (stage A)
    float* o_geo  = (float*)(wb + 16LL * MB);   // [16384,192]  = 12.6 MiB (stage A)

    // Pre-transposed bf16 weights (JIT, placed in regions dead at time of use):
    u16* WT_moe = (u16*)(wb + 30LL * MB);            // 64x512   (stage A; W1 slab tail)
    u16* WT_kve = (u16*)(wb + 30LL * MB + 131072);   // 3x128x512 (stage A)
    u16* WT_ikv = (u16*)(ob + 0LL  * MB);            // 1024x512 (pre-Kf; O0 slab, dead)
    u16* WT_iq  = (u16*)(wb + 0LL  * MB);            // 512x512  (post-Vf; npri dead)
    u16* WT_of  = (u16*)(ob + 16LL * MB);            // 512x512  (post-attn; Kf dead)
    u16* WT_qa  = (u16*)(wb + 16LL * MB);            // 512x512  (post-attn; Vf dead)
    u16* WT_d   = (u16*)(wb + 16LL * MB);            // 512x512  (post-attn2; v_a dead)

    dim3 blk(256);
    const float* fnull = nullptr;
    float* f32null = nullptr;
    u16* u16null = nullptr;

    // ---- Pre: transpose MoE-side weights (tiny) ----
    tr_bf<<<dim3(2, 16), blk, 0, stream>>>(W_moe, 64, 0, WT_moe, 0, 512);
    tr_bf<<<dim3(2, 16, 3), blk, 0, stream>>>(Wk_e, 64, 512LL * 64, WT_kve, 128LL * 512, 512);
    tr_bf<<<dim3(2, 16, 3), blk, 0, stream>>>(Wv_e, 64, 512LL * 64, WT_kve + 64 * 512, 128LL * 512, 512);

    // ---- A: MoE priori ----
    gemm_v5<float, float, float><<<dim3(1, 128), blk, 0, stream>>>(       // xs
        tag, 512, 0, WT_moe, 0, b_moe, fnull, fnull, 0,
        o_xs, f32null, 64, 0, 512, 64, 0);
    gemm_v5<float, float, float><<<dim3(1, 32, 3), blk, 0, stream>>>(     // k_e|v_e fused
        refs, 512, 4096LL * 512, WT_kve, 128LL * 512, fnull, fnull, fnull, 0,
        o_ke, o_ve, 64, 4096LL * 64, 512, 128, 64);
    gemm_mfma<float, float, float><<<dim3(1, 128, 3), blk, 0, stream>>>(  // q_e
        o_xs, 64, 0, Wq_e, 64, 4096LL, nullptr, fnull, 0,
        o_qe, 64, 16384LL * 64, 64, 64);
    moe_attn_k<<<dim3(3, 128), dim3(128), 0, stream>>>(                   // geo = gate*eo
        o_qe, o_ke, o_ve, o_xs, Wg, bg, o_geo);
    gemm_mfma<float, float, float><<<dim3(1, 128), blk, 0, stream>>>(     // priori = geo @ Wo_cat
        o_geo, 192, 0, Wo_e, 64, 0, nullptr, fnull, 0, o_pri, 64, 0, 192, 64);

    // ---- B: priori causal self-MHA + expansion to 512 ----
    ln64_k<<<dim3(4096), blk, 0, stream>>>(o_pri, g_np, b_np, o_np64, 16384);
    gemm_mfma<float, float, float><<<dim3(2, 128), blk, 0, stream>>>(     // qkv_p
        o_np64, 64, 0, Wi_p, 192, 0, bi_p, fnull, 0, o_qkv, 192, 0, 64, 192);
    attn_small_k<<<dim3(8, 128), dim3(128), 0, stream>>>(o_qkv, o_attp);
    gemm_mfma<float, float, float><<<dim3(1, 128), blk, 0, stream>>>(     // tmp64 (+res priori)
        o_attp, 64, 0, Wo_p, 64, 0, bo_p, o_pri, 64, o_tmp, 64, 0, 64, 64);
    gemm_mfma<float, float, u16><<<dim3(4, 128), blk, 0, stream>>>(       // priori_e -> W0
        o_tmp, 64, 0, W_pe, 512, 0, b_pe, fnull, 0, W0, 512, 0, 64, 512);

    // ---- C: fusion cross-MHA ----
    ln512_t<u16, u16><<<dim3(16384), blk, 0, stream>>>(W0, g_nh, b_nh, W0, 1e-5f); // npri
    tr_bf<<<dim3(32, 16), blk, 0, stream>>>(Wi_f + 512, 1536, 0, WT_ikv, 0, 512);  // K|V weights
    gemm_v5<u16, float, u16><<<dim3(4, 128), blk, 0, stream>>>(           // Kf -> O1
        W0, 512, 0, WT_ikv, 0, bi_f + 512, fnull, fnull, 0,
        O1, u16null, 512, 0, 512, 512, 0);
    gemm_v5<u16, float, u16><<<dim3(4, 128), blk, 0, stream>>>(           // Vf -> W1
        W0, 512, 0, WT_ikv + 512 * 512, 0, bi_f + 1024, fnull, fnull, 0,
        W1, u16null, 512, 0, 512, 512, 0);
    tr_bf<<<dim3(16, 16), blk, 0, stream>>>(Wi_f, 1536, 0, WT_iq, 0, 512);         // Q weights (npri dead)
    gemm_v5<float, float, u16><<<dim3(4, 128), blk, 0, stream>>>(         // Qf -> O0
        hidden, 512, 0, WT_iq, 0, bi_f, fnull, fnull, 0,
        O0, u16null, 512, 0, 512, 512, 0);
    attn_mfma_k<<<dim3(8, 128), dim3(256), 0, stream>>>(O0, O1, W1, W0, 128, 1);   // attn -> W0
    tr_bf<<<dim3(16, 16), blk, 0, stream>>>(Wo_f, 512, 0, WT_of, 0, 512);          // (Kf dead)
    gemm_v5<u16, float, u16><<<dim3(4, 128), blk, 0, stream>>>(           // hidden2 -> O0
        W0, 512, 0, WT_of, 0, bo_f, fnull, hidden, 512,
        O0, u16null, 512, 0, 512, 512, 0);

    // ---- D: feat cross-attention ----
    ln512_t<u16, u16><<<dim3(16384), blk, 0, stream>>>(O0, g_nfh, b_nfh, O0, 1e-5f); // nh
    tr_bf<<<dim3(16, 16), blk, 0, stream>>>(Wq_a, 512, 0, WT_qa, 0, 512);            // (Vf dead)
    gemm_v5<u16, float, u16><<<dim3(4, 128), blk, 0, stream>>>(           // q_a -> O1
        O0, 512, 0, WT_qa, 0, bq_a, fnull, fnull, 0,
        O1, u16null, 512, 0, 512, 512, 0);
    gemm_mfma<float, float, u16><<<dim3(4, 84), blk, 0, stream>>>(        // k_a -> W0
        feats, 512, 0, Wk_a, 512, 0, bk_a, fnull, 0, W0, 512, 0, 512, 512);
    gemm_mfma<float, float, u16><<<dim3(4, 84), blk, 0, stream>>>(        // v_a -> W1
        feats, 512, 0, Wv_a, 512, 0, bv_a, fnull, 0, W1, 512, 0, 512, 512);
    attn_mfma_k<<<dim3(8, 128), dim3(256), 0, stream>>>(O1, W0, W1, O1, 84, 0);    // ctx in-place
    tr_bf<<<dim3(16, 16), blk, 0, stream>>>(Wd, 512, 0, WT_d, 0, 512);             // (v_a dead)
    gemm_v5<u16, u16, u16><<<dim3(4, 128), blk, 0, stream>>>(             // ctxd -> W0 (+res nh)
        O1, 512, 0, WT_d, 0, bd, fnull, O0, 512,
        W0, u16null, 512, 0, 512, 512, 0);

    // ---- E: final post-LN (eps=1e-12) -> fp32 d_out ----
    ln512_t<u16, float><<<dim3(16384), blk, 0, stream>>>(W0, g_ln, b_ln, out, 1e-12f);
}

// Round 8
// 769.191 us; speedup vs baseline: 1.7792x; 1.1539x over previous
//
#include <hip/hip_runtime.h>
#include <hip/hip_bf16.h>

typedef unsigned short u16;
typedef unsigned int   u32;
typedef __attribute__((ext_vector_type(8))) short short8;   // 8 bf16 (4 VGPRs)
typedef __attribute__((ext_vector_type(4))) float f32x4;

#define BBt 128
#define SS 128
#define RR 32
#define NEx 3
#define MB (1024 * 1024)

static __device__ __forceinline__ float bs2f(u16 u){ return __uint_as_float(((u32)u) << 16); }
static __device__ __forceinline__ u16 f2bs(float x){
    u32 u = __float_as_uint(x);
    u += 0x7fff + ((u >> 16) & 1);          // RNE
    return (u16)(u >> 16);
}
static __device__ __forceinline__ u32 pkbf(float a, float b){   // pack 2 fp32 -> 2 bf16 (RNE)
    u32 r; asm("v_cvt_pk_bf16_f32 %0, %1, %2" : "=v"(r) : "v"(a), "v"(b)); return r;
}
static __device__ __forceinline__ float ldany(const float* p){ return *p; }
static __device__ __forceinline__ float ldany(const u16* p){ return bs2f(*p); }

// ===========================================================================
// Weight transpose+convert: dst[n][k] (bf16, ld=ldd) = src[k][n] (fp32, ld=lds_).
// Grid (N/32, K/32, z). One-shot per weight; runs once per forward.
// ===========================================================================
__global__ __launch_bounds__(256) void tr_bf(
    const float* __restrict__ src, int lds_, long long sSrc,
    u16* __restrict__ dst, long long sDst, int ldd)
{
    int z = blockIdx.z;
    src += (long long)z * sSrc;
    dst += (long long)z * sDst;
    int n0 = blockIdx.x * 32, k0 = blockIdx.y * 32;
    __shared__ u16 t[32][33];
    int c = threadIdx.x & 31, r0 = threadIdx.x >> 5;
    #pragma unroll
    for (int i = 0; i < 4; ++i) {
        int r = r0 + i * 8;
        t[r][c] = f2bs(src[(long long)(k0 + r) * lds_ + n0 + c]);
    }
    __syncthreads();
    int rr = threadIdx.x >> 3, kk = (threadIdx.x & 7) * 4;
    u16 o[4] = { t[kk][rr], t[kk+1][rr], t[kk+2][rr], t[kk+3][rr] };
    *(uint2*)&dst[(long long)(n0 + rr) * ldd + k0 + kk] = *(uint2*)o;
}

// ===========================================================================
// MFMA GEMM (BM=64): C[M,N] = A[M,K] @ W[K,N] (+bias) (+Res).
// BM=64, BN=128 (cols >= Ncols masked), BK=32, 256 threads (4 waves 2x2,
// each wave 32x64 of output). BM=64 doubles grid.y -> 4+ blocks/CU so
// barrier drains of one block overlap compute of another (latency-bound fix).
// A: fp32 or bf16. W: fp32 row-major (transposed to LDS). C: fp32 or bf16.
// M % 64 == 0, K % 32 == 0, Ncols % 8 == 0. Batched via z.
// ===========================================================================
template<typename TA, typename TRes, typename TC>
__global__ __launch_bounds__(256) void gemm_mfma(
    const TA* __restrict__ A, int lda, long long sA,
    const float* __restrict__ W, int ldw, long long sW,
    const float* __restrict__ bias,
    const TRes* __restrict__ Res, int ldr,
    TC* __restrict__ C, int ldc, long long sC,
    int K, int Ncols)
{
    int bz = blockIdx.z;
    A += (long long)bz * sA;
    W += (long long)bz * sW;
    C += (long long)bz * sC;

    __shared__ __align__(16) u16 As[64][40];    // [m][k]
    __shared__ __align__(16) u16 Bs[128][40];   // [n][k] (W transposed)

    int tid = threadIdx.x;
    long long row0 = (long long)blockIdx.y * 64;
    int col0 = blockIdx.x * 128;

    int wid = tid >> 6, lane = tid & 63;
    int wm = (wid >> 1) * 32, wn = (wid & 1) * 64;
    int l15 = lane & 15, quad = lane >> 4;

    f32x4 acc[2][4];
    #pragma unroll
    for (int i = 0; i < 2; ++i)
        #pragma unroll
        for (int j = 0; j < 4; ++j)
            acc[i][j] = (f32x4){0.f, 0.f, 0.f, 0.f};

    int ar = tid >> 2, ak = (tid & 3) * 8;           // A: 64 rows x 32k, 8 u16/thread
    int bk0 = (tid & 15) * 2, bn0 = (tid >> 4) * 8;  // B transpose map

    for (int kt = 0; kt < K; kt += 32) {
        {   // ---- stage A tile [64,32] -> bf16 ----
            const TA* src = A + (row0 + ar) * lda + kt + ak;
            if constexpr (sizeof(TA) == 4) {
                float4 f0 = *(const float4*)(src);
                float4 f1 = *(const float4*)(src + 4);
                u32 t[4] = {pkbf(f0.x,f0.y), pkbf(f0.z,f0.w), pkbf(f1.x,f1.y), pkbf(f1.z,f1.w)};
                *(uint4*)&As[ar][ak] = *(uint4*)t;
            } else {
                *(uint4*)&As[ar][ak] = *(const uint4*)(src);
            }
        }
        {   // ---- stage W tile [32,128] transposed -> Bs[n][k], N-guarded ----
            if (col0 + bn0 < Ncols) {
                const float* w0 = W + (long long)(kt + bk0) * ldw + col0 + bn0;
                const float* w1 = w0 + ldw;
                float r0[8], r1[8];
                *(float4*)&r0[0] = *(const float4*)(w0);
                *(float4*)&r0[4] = *(const float4*)(w0 + 4);
                *(float4*)&r1[0] = *(const float4*)(w1);
                *(float4*)&r1[4] = *(const float4*)(w1 + 4);
                #pragma unroll
                for (int i = 0; i < 8; ++i) {
                    u32 packed = (u32)f2bs(r0[i]) | ((u32)f2bs(r1[i]) << 16);
                    *(u32*)&Bs[bn0 + i][bk0] = packed;
                }
            } else {
                #pragma unroll
                for (int i = 0; i < 8; ++i)
                    *(u32*)&Bs[bn0 + i][bk0] = 0u;
            }
        }
        __syncthreads();

        short8 af[2], bfr[4];
        #pragma unroll
        for (int mt = 0; mt < 2; ++mt)
            af[mt] = *(const short8*)&As[wm + mt * 16 + l15][quad * 8];
        #pragma unroll
        for (int nt = 0; nt < 4; ++nt)
            bfr[nt] = *(const short8*)&Bs[wn + nt * 16 + l15][quad * 8];
        #pragma unroll
        for (int mt = 0; mt < 2; ++mt)
            #pragma unroll
            for (int nt = 0; nt < 4; ++nt)
                acc[mt][nt] = __builtin_amdgcn_mfma_f32_16x16x32_bf16(
                    af[mt], bfr[nt], acc[mt][nt], 0, 0, 0);
        __syncthreads();
    }

    // ---- epilogue: C/D layout col=lane&15, row=quad*4+reg ----
    #pragma unroll
    for (int mt = 0; mt < 2; ++mt) {
        #pragma unroll
        for (int r = 0; r < 4; ++r) {
            long long row = row0 + wm + mt * 16 + quad * 4 + r;
            #pragma unroll
            for (int nt = 0; nt < 4; ++nt) {
                int col = col0 + wn + nt * 16 + l15;
                if (col >= Ncols) continue;
                float v = acc[mt][nt][r];
                if (bias) v += bias[col];
                if (Res)  v += ldany(&Res[row * ldr + col]);
                if constexpr (sizeof(TC) == 4) C[row * ldc + col] = v;
                else                           C[row * ldc + col] = f2bs(v);
            }
        }
    }
}

// ===========================================================================
// MFMA GEMM v5 (BM=64): B from PRE-TRANSPOSED bf16 WT[Ncols][K] row-major —
// B staging is a straight coalesced uint4 row copy. Optional C2/bias2 column
// split at Nsplit (fused K|V projections). Same frag conventions as gemm_mfma.
// ===========================================================================
template<typename TA, typename TRes, typename TC>
__global__ __launch_bounds__(256) void gemm_v5(
    const TA* __restrict__ A, int lda, long long sA,
    const u16* __restrict__ WT, long long sW,
    const float* __restrict__ bias, const float* __restrict__ bias2,
    const TRes* __restrict__ Res, int ldr,
    TC* __restrict__ C, TC* __restrict__ C2, int ldc, long long sC,
    int K, int Ncols, int Nsplit)
{
    int bz = blockIdx.z;
    A += (long long)bz * sA;
    WT += (long long)bz * sW;
    C += (long long)bz * sC;
    if (C2) C2 += (long long)bz * sC;

    __shared__ __align__(16) u16 As[64][40];
    __shared__ __align__(16) u16 Bs[128][40];

    int tid = threadIdx.x;
    long long row0 = (long long)blockIdx.y * 64;
    int col0 = blockIdx.x * 128;

    int wid = tid >> 6, lane = tid & 63;
    int wm = (wid >> 1) * 32, wn = (wid & 1) * 64;
    int l15 = lane & 15, quad = lane >> 4;

    f32x4 acc[2][4];
    #pragma unroll
    for (int i = 0; i < 2; ++i)
        #pragma unroll
        for (int j = 0; j < 4; ++j)
            acc[i][j] = (f32x4){0.f, 0.f, 0.f, 0.f};

    int ar = tid >> 2, ak = (tid & 3) * 8;   // A map: 64 rows, 8 u16/thread
    int br = tid >> 1, bk = (tid & 1) * 16;  // B map: 128 rows, 16 u16/thread

    for (int kt = 0; kt < K; kt += 32) {
        {   // ---- stage A tile [64,32] -> bf16 ----
            const TA* src = A + (row0 + ar) * lda + kt + ak;
            if constexpr (sizeof(TA) == 4) {
                float4 f0 = *(const float4*)(src);
                float4 f1 = *(const float4*)(src + 4);
                u32 t[4] = {pkbf(f0.x,f0.y), pkbf(f0.z,f0.w), pkbf(f1.x,f1.y), pkbf(f1.z,f1.w)};
                *(uint4*)&As[ar][ak] = *(uint4*)t;
            } else {
                *(uint4*)&As[ar][ak] = *(const uint4*)(src);
            }
        }
        {   // ---- stage B tile: plain row copy from WT[n][k] ----
            int nr = col0 + br;
            if (nr < Ncols) {
                const u16* ws = WT + (long long)nr * K + kt + bk;
                *(uint4*)&Bs[br][bk]     = *(const uint4*)(ws);
                *(uint4*)&Bs[br][bk + 8] = *(const uint4*)(ws + 8);
            } else {
                uint4 z = {0u, 0u, 0u, 0u};
                *(uint4*)&Bs[br][bk] = z;
                *(uint4*)&Bs[br][bk + 8] = z;
            }
        }
        __syncthreads();

        short8 af[2], bfr[4];
        #pragma unroll
        for (int mt = 0; mt < 2; ++mt)
            af[mt] = *(const short8*)&As[wm + mt * 16 + l15][quad * 8];
        #pragma unroll
        for (int nt = 0; nt < 4; ++nt)
            bfr[nt] = *(const short8*)&Bs[wn + nt * 16 + l15][quad * 8];
        #pragma unroll
        for (int mt = 0; mt < 2; ++mt)
            #pragma unroll
            for (int nt = 0; nt < 4; ++nt)
                acc[mt][nt] = __builtin_amdgcn_mfma_f32_16x16x32_bf16(
                    af[mt], bfr[nt], acc[mt][nt], 0, 0, 0);
        __syncthreads();
    }

    // ---- epilogue: C/D layout col=lane&15, row=quad*4+reg; C2 split ----
    #pragma unroll
    for (int mt = 0; mt < 2; ++mt) {
        #pragma unroll
        for (int r = 0; r < 4; ++r) {
            long long row = row0 + wm + mt * 16 + quad * 4 + r;
            #pragma unroll
            for (int nt = 0; nt < 4; ++nt) {
                int col = col0 + wn + nt * 16 + l15;
                if (col >= Ncols) continue;
                float v = acc[mt][nt][r];
                if (bias2 && col >= Nsplit) v += bias2[col - Nsplit];
                else if (bias)              v += bias[col];
                if (Res) v += ldany(&Res[row * ldr + col]);
                TC* dst = (C2 && col >= Nsplit) ? (C2 + row * ldc + (col - Nsplit))
                                                : (C  + row * ldc + col);
                if constexpr (sizeof(TC) == 4) *dst = v;
                else                           *dst = f2bs(v);
            }
        }
    }
}

// ===========================================================================
// MFMA flash-less attention, bf16 in/out. Block per (head h, batch b).
// 4 waves x 32 query rows. out may alias Q.
// ===========================================================================
__global__ __launch_bounds__(256) void attn_mfma_k(
    const u16* __restrict__ Q, const u16* __restrict__ K,
    const u16* __restrict__ V, u16* __restrict__ out,
    int L, int causal)
{
    int h = blockIdx.x, b = blockIdx.y;
    int tid = threadIdx.x;
    int w = tid >> 6, lane = tid & 63;
    int l15 = lane & 15, quad = lane >> 4;

    int NTP = (L + 15) >> 4;          // padded kv tiles (6 or 8)
    int Lp  = NTP * 16;               // 96 or 128
    int ntmax = causal ? (2 * w + 1) : (NTP - 1);        // wave-uniform
    int ksmax = causal ? w : (((L + 31) >> 5) - 1);      // wave-uniform

    __shared__ __align__(16) u16 vT[64][136];            // V^T [d][kv], 17408 B
    __shared__ __align__(16) u16 pool[4][32][136];       // pS (aliases kS), 34816 B
    u16 (*kS)[72] = (u16(*)[72])&pool[0][0][0];          // [128][72] = 18432 B

    // ---- stage K natural [kv][d] (zero-pad rows >= L) ----
    for (int i = tid; i < Lp * 8; i += 256) {
        int r = i >> 3, c8 = i & 7;
        uint4 val = {0u, 0u, 0u, 0u};
        if (r < L) val = *(const uint4*)&K[((long long)b * L + r) * 512 + h * 64 + c8 * 8];
        *(uint4*)&kS[r][c8 * 8] = val;
    }
    // ---- stage V transposed [d][kv] (zero-pad kv >= L) ----
    for (int i = tid; i < 512; i += 256) {       // dg = i>>6 in 0..7, kp = i&63
        int kp = i & 63, dg = i >> 6;
        int kv0 = kp * 2;
        if (kv0 < Lp) {
            uint4 r0 = {0u,0u,0u,0u}, r1 = {0u,0u,0u,0u};
            if (kv0 < L)     r0 = *(const uint4*)&V[((long long)b * L + kv0    ) * 512 + h * 64 + dg * 8];
            if (kv0 + 1 < L) r1 = *(const uint4*)&V[((long long)b * L + kv0 + 1) * 512 + h * 64 + dg * 8];
            u32 w0[4] = {r0.x, r0.y, r0.z, r0.w};
            u32 w1[4] = {r1.x, r1.y, r1.z, r1.w};
            #pragma unroll
            for (int j = 0; j < 4; ++j) {
                *(u32*)&vT[dg * 8 + 2 * j    ][kv0] = (w0[j] & 0xffffu) | (w1[j] << 16);
                *(u32*)&vT[dg * 8 + 2 * j + 1][kv0] = (w0[j] >> 16) | (w1[j] & 0xffff0000u);
            }
        }
    }

    // ---- Q fragments direct from global (A-frag layout) ----
    short8 qf[2][2];
    #pragma unroll
    for (int mt = 0; mt < 2; ++mt)
        #pragma unroll
        for (int ks = 0; ks < 2; ++ks)
            qf[mt][ks] = *(const short8*)&Q[((long long)b * 128 + w * 32 + mt * 16 + l15) * 512
                                            + h * 64 + ks * 32 + quad * 8];
    __syncthreads();

    // ---- S = Q @ K^T (tiles guarded by wave-uniform ntmax) ----
    f32x4 sacc[2][8];
    #pragma unroll
    for (int mt = 0; mt < 2; ++mt)
        #pragma unroll
        for (int nt = 0; nt < 8; ++nt)
            sacc[mt][nt] = (f32x4){0.f, 0.f, 0.f, 0.f};
    #pragma unroll
    for (int nt = 0; nt < 8; ++nt) {
        if (nt <= ntmax) {
            short8 kf0 = *(const short8*)&kS[nt * 16 + l15][quad * 8];
            short8 kf1 = *(const short8*)&kS[nt * 16 + l15][32 + quad * 8];
            #pragma unroll
            for (int mt = 0; mt < 2; ++mt) {
                sacc[mt][nt] = __builtin_amdgcn_mfma_f32_16x16x32_bf16(qf[mt][0], kf0, sacc[mt][nt], 0, 0, 0);
                sacc[mt][nt] = __builtin_amdgcn_mfma_f32_16x16x32_bf16(qf[mt][1], kf1, sacc[mt][nt], 0, 0, 0);
            }
        }
    }

    // ---- softmax over rows (cols = l15 lanes x nt tiles); scale 1/8 folded ----
    float pm[2][4], ls[2][4];
    #pragma unroll
    for (int mt = 0; mt < 2; ++mt) {
        #pragma unroll
        for (int r = 0; r < 4; ++r) pm[mt][r] = -1e30f;
        #pragma unroll
        for (int nt = 0; nt < 8; ++nt) {
            if (nt <= ntmax) {
                int col = nt * 16 + l15;
                #pragma unroll
                for (int r = 0; r < 4; ++r) {
                    int rowq = w * 32 + mt * 16 + quad * 4 + r;
                    bool bad = (col >= L) || (causal && col > rowq);
                    float sv = bad ? -1e30f : sacc[mt][nt][r];
                    sacc[mt][nt][r] = sv;
                    pm[mt][r] = fmaxf(pm[mt][r], sv);
                }
            }
        }
        #pragma unroll
        for (int r = 0; r < 4; ++r) {
            float mx = pm[mt][r];
            #pragma unroll
            for (int o = 1; o <= 8; o <<= 1) mx = fmaxf(mx, __shfl_xor(mx, o));
            pm[mt][r] = mx * 0.125f;           // scaled max
            ls[mt][r] = 0.f;
        }
        #pragma unroll
        for (int nt = 0; nt < 8; ++nt) {
            if (nt <= ntmax) {
                #pragma unroll
                for (int r = 0; r < 4; ++r) {
                    float p = __expf(fmaf(sacc[mt][nt][r], 0.125f, -pm[mt][r]));
                    sacc[mt][nt][r] = p;
                    ls[mt][r] += p;
                }
            }
        }
        #pragma unroll
        for (int r = 0; r < 4; ++r) {
            float sm = ls[mt][r];
            #pragma unroll
            for (int o = 1; o <= 8; o <<= 1) sm += __shfl_xor(sm, o);
            ls[mt][r] = 1.f / sm;
        }
    }

    __syncthreads();   // kS dead -> reuse as per-wave P tiles

    // ---- P -> bf16 -> per-wave LDS (pack col pairs via shfl, even l15 writes) ----
    u16 (*pW)[136] = (u16(*)[136])&pool[w][0][0];
    bool wl = (l15 & 1) == 0;
    #pragma unroll
    for (int mt = 0; mt < 2; ++mt)
        #pragma unroll
        for (int nt = 0; nt < 8; ++nt) {
            if (nt <= ntmax) {
                #pragma unroll
                for (int r = 0; r < 4; ++r) {
                    float pv = sacc[mt][nt][r];
                    float po = __shfl_xor(pv, 1);
                    if (wl) {
                        u32 packed = (u32)f2bs(pv) | ((u32)f2bs(po) << 16);
                        *(u32*)&pW[mt * 16 + quad * 4 + r][nt * 16 + l15] = packed;
                    }
                }
            }
        }

    // ---- O = P @ V (A-frag from pW, B-frag from vT) ----
    f32x4 oacc[2][4];
    #pragma unroll
    for (int mt = 0; mt < 2; ++mt)
        #pragma unroll
        for (int nd = 0; nd < 4; ++nd)
            oacc[mt][nd] = (f32x4){0.f, 0.f, 0.f, 0.f};
    #pragma unroll
    for (int ks = 0; ks < 4; ++ks) {
        if (ks <= ksmax) {
            short8 pf0 = *(const short8*)&pW[l15     ][ks * 32 + quad * 8];
            short8 pf1 = *(const short8*)&pW[16 + l15][ks * 32 + quad * 8];
            #pragma unroll
            for (int nd = 0; nd < 4; ++nd) {
                short8 vf = *(const short8*)&vT[nd * 16 + l15][ks * 32 + quad * 8];
                oacc[0][nd] = __builtin_amdgcn_mfma_f32_16x16x32_bf16(pf0, vf, oacc[0][nd], 0, 0, 0);
                oacc[1][nd] = __builtin_amdgcn_mfma_f32_16x16x32_bf16(pf1, vf, oacc[1][nd], 0, 0, 0);
            }
        }
    }

    // ---- write out (pack col pairs via shfl, even l15 writes u32) ----
    #pragma unroll
    for (int mt = 0; mt < 2; ++mt)
        #pragma unroll
        for (int nd = 0; nd < 4; ++nd)
            #pragma unroll
            for (int r = 0; r < 4; ++r) {
                float ov = oacc[mt][nd][r] * ls[mt][r];
                float oo = __shfl_xor(ov, 1);
                if (wl) {
                    long long rowq = (long long)b * 128 + w * 32 + mt * 16 + quad * 4 + r;
                    u32 packed = (u32)f2bs(ov) | ((u32)f2bs(oo) << 16);
                    *(u32*)&out[rowq * 512 + h * 64 + nd * 16 + l15] = packed;
                }
            }
}

// ===========================================================================
// LayerNorm over 512, templated dtypes. In-place OK.
// ===========================================================================
template<typename TI, typename TO>
__global__ __launch_bounds__(256) void ln512_t(
    const TI* __restrict__ x, const float* __restrict__ g,
    const float* __restrict__ bt, TO* __restrict__ y, float eps)
{
    int row = blockIdx.x, tid = threadIdx.x;
    long long base = (long long)row * 512;
    float v0 = ldany(&x[base + tid]);
    float v1 = ldany(&x[base + 256 + tid]);
    float s = v0 + v1, ss = v0 * v0 + v1 * v1;
    #pragma unroll
    for (int o = 32; o >= 1; o >>= 1) { s += __shfl_xor(s, o); ss += __shfl_xor(ss, o); }
    __shared__ float red[2][4];
    int wave = tid >> 6, lane = tid & 63;
    if (lane == 0) { red[0][wave] = s; red[1][wave] = ss; }
    __syncthreads();
    s  = red[0][0] + red[0][1] + red[0][2] + red[0][3];
    ss = red[1][0] + red[1][1] + red[1][2] + red[1][3];
    float mean = s * (1.f / 512.f);
    float var = ss * (1.f / 512.f) - mean * mean;
    float rstd = rsqrtf(fmaxf(var, 0.f) + eps);
    float o0 = (v0 - mean) * rstd * g[tid]       + bt[tid];
    float o1 = (v1 - mean) * rstd * g[256 + tid] + bt[256 + tid];
    if constexpr (sizeof(TO) == 4) { y[base + tid] = o0; y[base + 256 + tid] = o1; }
    else { y[base + tid] = f2bs(o0); y[base + 256 + tid] = f2bs(o1); }
}

// ===========================================================================
// MoE expert attention: block = (expert e, batch b), thread = query s.
// Fuses the gate; writes geo[row, e*64+d] = gate_e(row) * eo_e[row,d].
// ===========================================================================
__global__ __launch_bounds__(128) void moe_attn_k(
    const float* __restrict__ qe,   // [3, B*S, 64]
    const float* __restrict__ ke,   // [3, B*R, 64]
    const float* __restrict__ ve,   // [3, B*R, 64]
    const float* __restrict__ xs,   // [B*S, 64] (for the gate)
    const float* __restrict__ Wg,   // [64,3]
    const float* __restrict__ bg,   // [3]
    float* __restrict__ geo)        // [B*S, 192]
{
    int e = blockIdx.x, b = blockIdx.y;
    int tid = threadIdx.x;
    __shared__ __align__(16) float kS[RR][64];
    __shared__ __align__(16) float vS[RR][64];

    {   // stage K/V tile for (e,b): 2048 floats each = 512 float4, coalesced
        const float4* ks = (const float4*)&ke[((long long)e * (BBt * RR) + (long long)b * RR) * 64];
        const float4* vs = (const float4*)&ve[((long long)e * (BBt * RR) + (long long)b * RR) * 64];
        float4* kd = (float4*)&kS[0][0];
        float4* vd = (float4*)&vS[0][0];
        #pragma unroll
        for (int t = 0; t < 4; ++t) {
            kd[tid + 128 * t] = ks[tid + 128 * t];
            vd[tid + 128 * t] = vs[tid + 128 * t];
        }
    }

    long long row = (long long)b * SS + tid;
    float q[64];
    {
        const float4* qp = (const float4*)&qe[((long long)e * (BBt * SS) + row) * 64];
        #pragma unroll
        for (int t = 0; t < 16; ++t) {
            float4 f = qp[t];
            q[4*t] = f.x; q[4*t+1] = f.y; q[4*t+2] = f.z; q[4*t+3] = f.w;
        }
    }

    // gate = softmax(xs_row @ Wg + bg)[e]
    float l0 = bg[0], l1 = bg[1], l2 = bg[2];
    {
        const float4* xr = (const float4*)&xs[row * 64];
        #pragma unroll
        for (int t = 0; t < 16; ++t) {
            float4 f = xr[t];
            float xv[4] = {f.x, f.y, f.z, f.w};
            #pragma unroll
            for (int u = 0; u < 4; ++u) {
                int j = 4 * t + u;
                l0 = fmaf(xv[u], Wg[j * 3 + 0], l0);
                l1 = fmaf(xv[u], Wg[j * 3 + 1], l1);
                l2 = fmaf(xv[u], Wg[j * 3 + 2], l2);
            }
        }
    }
    float mg = fmaxf(l0, fmaxf(l1, l2));
    float g0 = __expf(l0 - mg), g1 = __expf(l1 - mg), g2 = __expf(l2 - mg);
    float gate = (e == 0 ? g0 : (e == 1 ? g1 : g2)) / (g0 + g1 + g2);

    __syncthreads();

    // scores (two-pass softmax, all in registers)
    float s[RR];
    #pragma unroll
    for (int r = 0; r < RR; ++r) {
        float a0 = 0.f, a1 = 0.f, a2 = 0.f, a3 = 0.f;
        const float4* kr = (const float4*)&kS[r][0];
        #pragma unroll
        for (int t = 0; t < 16; ++t) {
            float4 f = kr[t];
            a0 = fmaf(q[4*t],   f.x, a0);
            a1 = fmaf(q[4*t+1], f.y, a1);
            a2 = fmaf(q[4*t+2], f.z, a2);
            a3 = fmaf(q[4*t+3], f.w, a3);
        }
        s[r] = ((a0 + a1) + (a2 + a3)) * 0.125f;   // 1/sqrt(64)
    }
    float m = s[0];
    #pragma unroll
    for (int r = 1; r < RR; ++r) m = fmaxf(m, s[r]);
    float l = 0.f;
    #pragma unroll
    for (int r = 0; r < RR; ++r) { s[r] = __expf(s[r] - m); l += s[r]; }
    float scale = gate / l;

    // PV
    float acc[64];
    #pragma unroll
    for (int d = 0; d < 64; ++d) acc[d] = 0.f;
    #pragma unroll
    for (int r = 0; r < RR; ++r) {
        float p = s[r];
        const float4* vr = (const float4*)&vS[r][0];
        #pragma unroll
        for (int t = 0; t < 16; ++t) {
            float4 f = vr[t];
            acc[4*t]   = fmaf(p, f.x, acc[4*t]);
            acc[4*t+1] = fmaf(p, f.y, acc[4*t+1]);
            acc[4*t+2] = fmaf(p, f.z, acc[4*t+2]);
            acc[4*t+3] = fmaf(p, f.w, acc[4*t+3]);
        }
    }
    float4* op = (float4*)&geo[row * 192 + e * 64];
    #pragma unroll
    for (int t = 0; t < 16; ++t) {
        float4 f;
        f.x = acc[4*t] * scale;   f.y = acc[4*t+1] * scale;
        f.z = acc[4*t+2] * scale; f.w = acc[4*t+3] * scale;
        op[t] = f;
    }
}

// ===========================================================================
// Small causal MHA on 64-dim priori (H=8, dh=8, S=128). qkv packed [B*S,192].
// ===========================================================================
__global__ __launch_bounds__(128) void attn_small_k(
    const float* __restrict__ qkv, float* __restrict__ out)
{
    int h = blockIdx.x, b = blockIdx.y;
    int tid = threadIdx.x;
    __shared__ float kS[SS][9], vS[SS][9];
    long long base = ((long long)b * SS + tid) * 192;
    #pragma unroll
    for (int d = 0; d < 8; ++d) {
        kS[tid][d] = qkv[base + 64 + h * 8 + d];
        vS[tid][d] = qkv[base + 128 + h * 8 + d];
    }
    float q[8];
    #pragma unroll
    for (int d = 0; d < 8; ++d)
        q[d] = qkv[base + h * 8 + d] * 0.35355339059327373f;
    __syncthreads();

    float m = -1e30f, l = 0.f, acc[8] = {};
    for (int j = 0; j <= tid; ++j) {
        float s = 0.f;
        #pragma unroll
        for (int d = 0; d < 8; ++d) s = fmaf(q[d], kS[j][d], s);
        float mn = fmaxf(m, s);
        float corr = __expf(m - mn);
        float p = __expf(s - mn);
        l = l * corr + p;
        #pragma unroll
        for (int d = 0; d < 8; ++d) acc[d] = fmaf(p, vS[j][d], acc[d] * corr);
        m = mn;
    }
    float inv = 1.f / l;
    #pragma unroll
    for (int d = 0; d < 8; ++d)
        out[((long long)b * SS + tid) * 64 + h * 8 + d] = acc[d] * inv;
}

__global__ __launch_bounds__(256) void ln64_k(
    const float* __restrict__ x, const float* __restrict__ g,
    const float* __restrict__ bt, float* __restrict__ y, int M)
{
    int wave = threadIdx.x >> 6, lane = threadIdx.x & 63;
    int row = blockIdx.x * 4 + wave;
    if (row >= M) return;
    long long base = (long long)row * 64;
    float v = x[base + lane];
    float s = v, ss = v * v;
    #pragma unroll
    for (int o = 32; o >= 1; o >>= 1) { s += __shfl_xor(s, o); ss += __shfl_xor(ss, o); }
    float mean = s * (1.f / 64.f);
    float var = ss * (1.f / 64.f) - mean * mean;
    float rstd = rsqrtf(fmaxf(var, 0.f) + 1e-5f);
    y[base + lane] = (v - mean) * rstd * g[lane] + bt[lane];
}

// ===========================================================================
extern "C" void kernel_launch(void* const* d_in, const int* in_sizes, int n_in,
                              void* d_out, int out_size, void* d_ws, size_t ws_size,
                              hipStream_t stream)
{
    (void)in_sizes; (void)n_in; (void)out_size; (void)ws_size;
    const float* hidden = (const float*)d_in[0];
    const float* tag    = (const float*)d_in[1];
    const float* feats  = (const float*)d_in[2];
    const float* refs   = (const float*)d_in[3];
    const float* W_moe  = (const float*)d_in[4];
    const float* b_moe  = (const float*)d_in[5];
    const float* Wg     = (const float*)d_in[6];
    const float* bg     = (const float*)d_in[7];
    const float* Wq_e   = (const float*)d_in[8];
    const float* Wk_e   = (const float*)d_in[9];
    const float* Wv_e   = (const float*)d_in[10];
    const float* Wo_e   = (const float*)d_in[11];
    const float* g_np   = (const float*)d_in[12];
    const float* b_np   = (const float*)d_in[13];
    const float* Wi_p   = (const float*)d_in[14];
    const float* bi_p   = (const float*)d_in[15];
    const float* Wo_p   = (const float*)d_in[16];
    const float* bo_p   = (const float*)d_in[17];
    const float* W_pe   = (const float*)d_in[18];
    const float* b_pe   = (const float*)d_in[19];
    const float* g_nh   = (const float*)d_in[20];
    const float* b_nh   = (const float*)d_in[21];
    const float* Wi_f   = (const float*)d_in[22];
    const float* bi_f   = (const float*)d_in[23];
    const float* Wo_f   = (const float*)d_in[24];
    const float* bo_f   = (const float*)d_in[25];
    const float* g_nfh  = (const float*)d_in[26];
    const float* b_nfh  = (const float*)d_in[27];
    const float* Wq_a   = (const float*)d_in[28];
    const float* bq_a   = (const float*)d_in[29];
    const float* Wk_a   = (const float*)d_in[30];
    const float* bk_a   = (const float*)d_in[31];
    const float* Wv_a   = (const float*)d_in[32];
    const float* bv_a   = (const float*)d_in[33];
    const float* Wd     = (const float*)d_in[34];
    const float* bd     = (const float*)d_in[35];
    const float* g_ln   = (const float*)d_in[36];
    const float* b_ln   = (const float*)d_in[37];
    float* out = (float*)d_out;
    char* ob = (char*)d_out;
    char* wb = (char*)d_ws;

    // bf16 slabs: ws = W0|W1 (16 MiB each); d_out doubles as O0|O1.
    u16* W0 = (u16*)(wb + 0LL * 16 * MB);
    u16* W1 = (u16*)(wb + 1LL * 16 * MB);
    u16* O0 = (u16*)(ob + 0LL * 16 * MB);
    u16* O1 = (u16*)(ob + 1LL * 16 * MB);

    // fp32 scratch (stage A/B) in lifetime-dead regions (stream-serialized):
    float* o_xs   = (float*)(ob + 0LL  * MB);
    float* o_ke   = (float*)(ob + 4LL  * MB);
    float* o_ve   = (float*)(ob + 7LL  * MB);
    float* o_pri  = (float*)(ob + 10LL * MB);
    float* o_np64 = (float*)(ob + 14LL * MB);
    float* o_qkv  = (float*)(ob + 18LL * MB);
    float* o_attp = (float*)(ob + 0LL  * MB);
    float* o_tmp  = (float*)(ob + 4LL  * MB);
    float* o_qe   = (float*)(wb + 0LL  * MB);   // [3,16384,64] = 12 MiB (stage A)
    float* o_geo  = (float*)(wb + 16LL * MB);   // [16384,192]  = 12.6 MiB (stage A)

    // Pre-transposed bf16 weights (JIT, placed in regions dead at time of use):
    u16* WT_moe = (u16*)(wb + 30LL * MB);            // 64x512   (stage A; W1 slab tail)
    u16* WT_kve = (u16*)(wb + 30LL * MB + 131072);   // 3x128x512 (stage A)
    u16* WT_ikv = (u16*)(ob + 0LL  * MB);            // 1024x512 (pre-Kf; O0 slab, dead)
    u16* WT_iq  = (u16*)(wb + 0LL  * MB);            // 512x512  (post-Vf; npri dead)
    u16* WT_of  = (u16*)(ob + 16LL * MB);            // 512x512  (post-attn; Kf dead)
    u16* WT_qa  = (u16*)(wb + 16LL * MB);            // 512x512  (post-attn; Vf dead)
    u16* WT_d   = (u16*)(wb + 16LL * MB);            // 512x512  (post-attn2; v_a dead)

    dim3 blk(256);
    const float* fnull = nullptr;
    float* f32null = nullptr;
    u16* u16null = nullptr;

    // ---- Pre: transpose MoE-side weights (tiny) ----
    tr_bf<<<dim3(2, 16), blk, 0, stream>>>(W_moe, 64, 0, WT_moe, 0, 512);
    tr_bf<<<dim3(2, 16, 3), blk, 0, stream>>>(Wk_e, 64, 512LL * 64, WT_kve, 128LL * 512, 512);
    tr_bf<<<dim3(2, 16, 3), blk, 0, stream>>>(Wv_e, 64, 512LL * 64, WT_kve + 64 * 512, 128LL * 512, 512);

    // ---- A: MoE priori ----
    gemm_v5<float, float, float><<<dim3(1, 256), blk, 0, stream>>>(       // xs
        tag, 512, 0, WT_moe, 0, b_moe, fnull, fnull, 0,
        o_xs, f32null, 64, 0, 512, 64, 0);
    gemm_v5<float, float, float><<<dim3(1, 64, 3), blk, 0, stream>>>(     // k_e|v_e fused
        refs, 512, 4096LL * 512, WT_kve, 128LL * 512, fnull, fnull, fnull, 0,
        o_ke, o_ve, 64, 4096LL * 64, 512, 128, 64);
    gemm_mfma<float, float, float><<<dim3(1, 256, 3), blk, 0, stream>>>(  // q_e
        o_xs, 64, 0, Wq_e, 64, 4096LL, nullptr, fnull, 0,
        o_qe, 64, 16384LL * 64, 64, 64);
    moe_attn_k<<<dim3(3, 128), dim3(128), 0, stream>>>(                   // geo = gate*eo
        o_qe, o_ke, o_ve, o_xs, Wg, bg, o_geo);
    gemm_mfma<float, float, float><<<dim3(1, 256), blk, 0, stream>>>(     // priori = geo @ Wo_cat
        o_geo, 192, 0, Wo_e, 64, 0, nullptr, fnull, 0, o_pri, 64, 0, 192, 64);

    // ---- B: priori causal self-MHA + expansion to 512 ----
    ln64_k<<<dim3(4096), blk, 0, stream>>>(o_pri, g_np, b_np, o_np64, 16384);
    gemm_mfma<float, float, float><<<dim3(2, 256), blk, 0, stream>>>(     // qkv_p
        o_np64, 64, 0, Wi_p, 192, 0, bi_p, fnull, 0, o_qkv, 192, 0, 64, 192);
    attn_small_k<<<dim3(8, 128), dim3(128), 0, stream>>>(o_qkv, o_attp);
    gemm_mfma<float, float, float><<<dim3(1, 256), blk, 0, stream>>>(     // tmp64 (+res priori)
        o_attp, 64, 0, Wo_p, 64, 0, bo_p, o_pri, 64, o_tmp, 64, 0, 64, 64);
    gemm_mfma<float, float, u16><<<dim3(4, 256), blk, 0, stream>>>(       // priori_e -> W0
        o_tmp, 64, 0, W_pe, 512, 0, b_pe, fnull, 0, W0, 512, 0, 64, 512);

    // ---- C: fusion cross-MHA ----
    ln512_t<u16, u16><<<dim3(16384), blk, 0, stream>>>(W0, g_nh, b_nh, W0, 1e-5f); // npri
    tr_bf<<<dim3(32, 16), blk, 0, stream>>>(Wi_f + 512, 1536, 0, WT_ikv, 0, 512);  // K|V weights
    gemm_v5<u16, float, u16><<<dim3(8, 256), blk, 0, stream>>>(           // Kf->O1 | Vf->W1 fused
        W0, 512, 0, WT_ikv, 0, bi_f + 512, bi_f + 1024, fnull, 0,
        O1, W1, 512, 0, 512, 1024, 512);
    tr_bf<<<dim3(16, 16), blk, 0, stream>>>(Wi_f, 1536, 0, WT_iq, 0, 512);         // Q weights (npri dead)
    gemm_v5<float, float, u16><<<dim3(4, 256), blk, 0, stream>>>(         // Qf -> O0
        hidden, 512, 0, WT_iq, 0, bi_f, fnull, fnull, 0,
        O0, u16null, 512, 0, 512, 512, 0);
    attn_mfma_k<<<dim3(8, 128), dim3(256), 0, stream>>>(O0, O1, W1, W0, 128, 1);   // attn -> W0
    tr_bf<<<dim3(16, 16), blk, 0, stream>>>(Wo_f, 512, 0, WT_of, 0, 512);          // (Kf dead)
    gemm_v5<u16, float, u16><<<dim3(4, 256), blk, 0, stream>>>(           // hidden2 -> O0
        W0, 512, 0, WT_of, 0, bo_f, fnull, hidden, 512,
        O0, u16null, 512, 0, 512, 512, 0);

    // ---- D: feat cross-attention ----
    ln512_t<u16, u16><<<dim3(16384), blk, 0, stream>>>(O0, g_nfh, b_nfh, O0, 1e-5f); // nh
    tr_bf<<<dim3(16, 16), blk, 0, stream>>>(Wq_a, 512, 0, WT_qa, 0, 512);            // (Vf dead)
    gemm_v5<u16, float, u16><<<dim3(4, 256), blk, 0, stream>>>(           // q_a -> O1
        O0, 512, 0, WT_qa, 0, bq_a, fnull, fnull, 0,
        O1, u16null, 512, 0, 512, 512, 0);
    gemm_mfma<float, float, u16><<<dim3(4, 168), blk, 0, stream>>>(       // k_a -> W0
        feats, 512, 0, Wk_a, 512, 0, bk_a, fnull, 0, W0, 512, 0, 512, 512);
    gemm_mfma<float, float, u16><<<dim3(4, 168), blk, 0, stream>>>(       // v_a -> W1
        feats, 512, 0, Wv_a, 512, 0, bv_a, fnull, 0, W1, 512, 0, 512, 512);
    attn_mfma_k<<<dim3(8, 128), dim3(256), 0, stream>>>(O1, W0, W1, O1, 84, 0);    // ctx in-place
    tr_bf<<<dim3(16, 16), blk, 0, stream>>>(Wd, 512, 0, WT_d, 0, 512);             // (v_a dead)
    gemm_v5<u16, u16, u16><<<dim3(4, 256), blk, 0, stream>>>(             // ctxd -> W0 (+res nh)
        O1, 512, 0, WT_d, 0, bd, fnull, O0, 512,
        W0, u16null, 512, 0, 512, 512, 0);

    // ---- E: final post-LN (eps=1e-12) -> fp32 d_out ----
    ln512_t<u16, float><<<dim3(16384), blk, 0, stream>>>(W0, g_ln, b_ln, out, 1e-12f);
}